// Round 11
// baseline (223.041 us; speedup 1.0000x reference)
//
#include <hip/hip_runtime.h>
#include <math.h>

#define D_INN 256
#define D_HID 64
#define DTR 16
#define D_MEMM 128
#define BB 2
#define LL 2048
#define NROWS (BB*LL)   // 4096
#define NPROJ 736
#define NTOT 864        // 736 proj cols + 128 Q cols
#define SEG 16
#define SEGLEN (LL/SEG) // 128
#define NCHUNK (LL/8)   // 256 8-step chunks per batch

typedef __attribute__((ext_vector_type(8))) short short8v;
typedef __attribute__((ext_vector_type(4))) float float4v;

static __device__ __forceinline__ unsigned short f2bf(float f) {
    unsigned int u = __float_as_uint(f);
    u += 0x7fff + ((u >> 16) & 1);   // RNE
    return (unsigned short)(u >> 16);
}

static __device__ __forceinline__ float rdlane(float v, int l) {
    return __uint_as_float(__builtin_amdgcn_readlane(__float_as_uint(v), l));
}

// packed index: (((g*BB + b)*NCHUNK + chunk)*64 + n)*8 + li   (g: 0=B, 1=Bl, 2=C)
#define PK(g, b, chunk, n, li) (((((size_t)(g)*BB + (b)) * NCHUNK + (chunk)) * 64 + (n)) * 8 + (li))

// ---------------- Kernel 1: proj = x @ [W_xproj | W_Q] (+b_Q), bf16 MFMA ----------------
// cols 0..191 (B, Bl, C) are written straight into the scan-packed layout.
__global__ __launch_bounds__(256) void k_gemm(const float* __restrict__ x,
        const float* __restrict__ Wx, const float* __restrict__ Wq,
        const float* __restrict__ bq, float* __restrict__ proj,
        float* __restrict__ packed) {
    __shared__ unsigned short As[64][40];
    __shared__ unsigned short Bs[64][40];
    const int t = threadIdx.x;
    const int lane = t & 63, w = t >> 6;
    const int wr = w >> 1, wc = w & 1;
    const int row0 = blockIdx.y * 64, col0 = blockIdx.x * 64;

    float4v acc[2][2];
    #pragma unroll
    for (int i = 0; i < 2; i++)
        #pragma unroll
        for (int j = 0; j < 2; j++) acc[i][j] = (float4v)0.f;

    const int ar = t >> 2, akq = (t & 3) * 8;
    const int bk = t >> 3, bcq = (t & 7) * 8;

    for (int k0 = 0; k0 < D_INN; k0 += 32) {
        float4 a0 = *(const float4*)&x[(size_t)(row0 + ar) * D_INN + k0 + akq];
        float4 a1 = *(const float4*)&x[(size_t)(row0 + ar) * D_INN + k0 + akq + 4];
        float4 b0 = {}, b1 = {};
        int col = col0 + bcq;
        if (col + 8 <= NPROJ) {
            b0 = *(const float4*)&Wx[(size_t)(k0 + bk) * NPROJ + col];
            b1 = *(const float4*)&Wx[(size_t)(k0 + bk) * NPROJ + col + 4];
        } else if (col < NTOT) {
            b0 = *(const float4*)&Wq[(size_t)(k0 + bk) * D_MEMM + (col - NPROJ)];
            b1 = *(const float4*)&Wq[(size_t)(k0 + bk) * D_MEMM + (col - NPROJ) + 4];
        }
        __syncthreads();
        {
            unsigned short av[8] = { f2bf(a0.x), f2bf(a0.y), f2bf(a0.z), f2bf(a0.w),
                                     f2bf(a1.x), f2bf(a1.y), f2bf(a1.z), f2bf(a1.w) };
            *(short8v*)&As[ar][akq] = *(short8v*)av;
            Bs[bcq + 0][bk] = f2bf(b0.x); Bs[bcq + 1][bk] = f2bf(b0.y);
            Bs[bcq + 2][bk] = f2bf(b0.z); Bs[bcq + 3][bk] = f2bf(b0.w);
            Bs[bcq + 4][bk] = f2bf(b1.x); Bs[bcq + 5][bk] = f2bf(b1.y);
            Bs[bcq + 6][bk] = f2bf(b1.z); Bs[bcq + 7][bk] = f2bf(b1.w);
        }
        __syncthreads();
        short8v af[2], bf[2];
        const int fr = lane & 15, fk = (lane >> 4) * 8;
        af[0] = *(short8v*)&As[wr * 32 + fr][fk];
        af[1] = *(short8v*)&As[wr * 32 + 16 + fr][fk];
        bf[0] = *(short8v*)&Bs[wc * 32 + fr][fk];
        bf[1] = *(short8v*)&Bs[wc * 32 + 16 + fr][fk];
        #pragma unroll
        for (int i = 0; i < 2; i++)
            #pragma unroll
            for (int j = 0; j < 2; j++)
                acc[i][j] = __builtin_amdgcn_mfma_f32_16x16x32_bf16(af[i], bf[j], acc[i][j], 0, 0, 0);
    }
    #pragma unroll
    for (int i = 0; i < 2; i++)
        #pragma unroll
        for (int j = 0; j < 2; j++) {
            int cc = col0 + wc * 32 + j * 16 + (lane & 15);
            int rr0 = row0 + wr * 32 + i * 16 + (lane >> 4) * 4;
            if (cc < 192) {   // B / Bl / C -> packed layout (whole 64-col tile is < 192)
                int g = cc >> 6, n = cc & 63;
                int bb = rr0 >> 11, l = rr0 & (LL - 1);
                float4 pk = make_float4(acc[i][j][0], acc[i][j][1], acc[i][j][2], acc[i][j][3]);
                *(float4*)&packed[PK(g, bb, l >> 3, n, l & 7)] = pk;
            } else {
                #pragma unroll
                for (int e = 0; e < 4; e++) {
                    float v = acc[i][j][e];
                    if (cc >= NPROJ) v += bq[cc - NPROJ];
                    proj[(size_t)(rr0 + e) * NTOT + cc] = v;
                }
            }
        }
}

// ---------------- Kernel 1b: xT[b][d][l] = x[b][l][d] (64x64 LDS transpose) ----------------
__global__ __launch_bounds__(256) void k_xt(const float* __restrict__ x,
        float* __restrict__ xT) {
    __shared__ float tile[64][65];
    const int t = threadIdx.x;
    const int lt = blockIdx.x * 64, dt = blockIdx.y * 64, b = blockIdx.z;
    const int c = t & 63, rg = (t >> 6) * 16;
    #pragma unroll
    for (int j = 0; j < 16; ++j)
        tile[rg + j][c] = x[((size_t)b * LL + lt + rg + j) * D_INN + dt + c];
    __syncthreads();
    #pragma unroll
    for (int j = 0; j < 16; ++j)
        xT[((size_t)b * D_INN + dt + rg + j) * LL + lt + c] = tile[c][rg + j];
}

// ---------------- Kernel 2: delta / delta_l, transposed outputs [d][l] ----------------
__global__ __launch_bounds__(256) void k_delta(const float* __restrict__ proj,
        const float* __restrict__ Wdt, const float* __restrict__ bdt,
        const float* __restrict__ Wdtl, const float* __restrict__ bdtl,
        float* __restrict__ deltaT, float* __restrict__ deltalT) {
    __shared__ float sdt[16][17], sdtl[16][17];
    const int t = threadIdx.x;
    const int r0 = blockIdx.x * 16;
    const int b = r0 >> 11, l0 = r0 & (LL - 1);
    {
        int r = t >> 4, c = t & 15;
        sdt[r][c]  = proj[(size_t)(r0 + r) * NTOT + 704 + c];
        sdtl[r][c] = proj[(size_t)(r0 + r) * NTOT + 720 + c];
    }
    __syncthreads();
    float w1[DTR], w2[DTR];
    #pragma unroll
    for (int r = 0; r < DTR; r++) {
        w1[r] = Wdt[r * D_INN + t];
        w2[r] = Wdtl[r * D_INN + t];
    }
    const float b1 = bdt[t], b2 = bdtl[t];
    float o1[16], o2[16];
    #pragma unroll
    for (int row = 0; row < 16; ++row) {
        float a1 = b1, a2 = b2;
        #pragma unroll
        for (int r = 0; r < DTR; r++) {
            a1 += sdt[row][r] * w1[r];
            a2 += sdtl[row][r] * w2[r];
        }
        o1[row] = (a1 > 20.f) ? a1 : log1pf(expf(a1));
        o2[row] = (a2 > 20.f) ? a2 : log1pf(expf(a2));
    }
    float* p1 = &deltaT[((size_t)b * D_INN + t) * LL + l0];
    float* p2 = &deltalT[((size_t)b * D_INN + t) * LL + l0];
    #pragma unroll
    for (int j = 0; j < 16; j += 4) {
        *(float4*)&p1[j] = make_float4(o1[j], o1[j+1], o1[j+2], o1[j+3]);
        *(float4*)&p2[j] = make_float4(o2[j], o2[j+1], o2[j+2], o2[j+3]);
    }
}

// ---------------- Kernel 3a: pass 1, templated on scan; packed B; peeled checkpoint ----
template<int SCAN>
__global__ __launch_bounds__(256) void k_scan1t(const float* __restrict__ xT,
        const float* __restrict__ packed, const float* __restrict__ A,
        const float* __restrict__ dTall,
        float* __restrict__ Qbuf, float* __restrict__ SDbuf,
        float* __restrict__ cumd, float* __restrict__ mem) {
    const int t = threadIdx.x;
    const int w = t >> 6, n = t & 63;
    const int b = blockIdx.y, seg = blockIdx.z;
    const int d = blockIdx.x * 4 + w;
    const float* dT = dTall + ((size_t)b * D_INN + d) * LL + seg * SEGLEN;
    const float* uT = xT + ((size_t)b * D_INN + d) * LL + seg * SEGLEN;
    const float Aln = A[d * D_HID + n] * 1.44269504f;
    const int lr = n & 7;
    const float* Bp = packed + PK(SCAN, b, seg * 16, 0, 0);

    float s = 0.f, sd = 0.f;
    for (int c = 0; c < 16; ++c) {
        float dvl = dT[c * 8 + lr];
        float pl  = dvl * uT[c * 8 + lr];
        float4 B0 = *(const float4*)&Bp[((size_t)c * 64 + n) * 8];
        float4 B1 = *(const float4*)&Bp[((size_t)c * 64 + n) * 8 + 4];
        float Bv[8] = {B0.x, B0.y, B0.z, B0.w, B1.x, B1.y, B1.z, B1.w};
        // step 0 peeled (checkpoint site)
        {
            float dv = rdlane(dvl, 0), p = rdlane(pl, 0);
            s = fmaf(exp2f(dv * Aln), s, p * Bv[0]);
            sd += dv;
        }
        if (SCAN == 1 && (c & 1) == 0) {
            float v = s;
            #pragma unroll
            for (int off = 32; off >= 1; off >>= 1) v += __shfl_xor(v, off);
            if (n == 0) {
                int k = seg * 8 + (c >> 1);
                mem[((size_t)b * 128 + k) * D_INN + d] = v;
                cumd[(((size_t)b * SEG + seg) * 8 + (c >> 1)) * D_INN + d] = sd;
            }
        }
        #pragma unroll
        for (int li = 1; li < 8; ++li) {
            float dv = rdlane(dvl, li), p = rdlane(pl, li);
            s = fmaf(exp2f(dv * Aln), s, p * Bv[li]);
            sd += dv;
        }
    }
    Qbuf[((((size_t)SCAN * 2 + b) * SEG + seg) * D_INN + d) * 64 + n] = s;
    if (n == 0) SDbuf[(((size_t)SCAN * 2 + b) * SEG + seg) * D_INN + d] = sd;
}

// ---------------- Kernel 3b: pass 2 — scan 0 only, packed B/C ----------------
__global__ __launch_bounds__(256) void k_scan2(const float* __restrict__ xT,
        const float* __restrict__ packed, const float* __restrict__ A,
        const float* __restrict__ Dp, const float* __restrict__ deltaT,
        const float* __restrict__ Qbuf, const float* __restrict__ SDbuf,
        float* __restrict__ y) {
    __shared__ float rbuf[4][8][65];
    const int t = threadIdx.x;
    const int w = t >> 6, n = t & 63;
    const int b = blockIdx.y, seg = blockIdx.z;
    const int d = blockIdx.x * 4 + w;
    const size_t rowbase = (size_t)b * LL + (size_t)seg * SEGLEN;
    const float* dT = deltaT + ((size_t)b * D_INN + d) * LL + seg * SEGLEN;
    const float* uT = xT + ((size_t)b * D_INN + d) * LL + seg * SEGLEN;
    const float Aln = A[d * D_HID + n] * 1.44269504f;
    const float Dpv = Dp[d];
    const int lr = n & 7;
    const int rli = n >> 3, g = n & 7;
    const float* Bp = packed + PK(0, b, seg * 16, 0, 0);
    const float* Cp = packed + PK(2, b, seg * 16, 0, 0);

    // s_in prefix over earlier segments (scan 0)
    float s = 0.f;
    for (int k = 0; k < seg; ++k) {
        float sdk = SDbuf[(((size_t)b * SEG + k) * D_INN + d)];
        float Qk = Qbuf[(((size_t)b * SEG + k) * D_INN + d) * 64 + n];
        s = fmaf(exp2f(sdk * Aln), s, Qk);
    }

    for (int c = 0; c < 16; ++c) {
        const size_t l0 = rowbase + c * 8;
        float dvl = dT[c * 8 + lr];
        float uvl = uT[c * 8 + lr];
        float pl = dvl * uvl;
        float4 B0 = *(const float4*)&Bp[((size_t)c * 64 + n) * 8];
        float4 B1 = *(const float4*)&Bp[((size_t)c * 64 + n) * 8 + 4];
        float4 C0 = *(const float4*)&Cp[((size_t)c * 64 + n) * 8];
        float4 C1 = *(const float4*)&Cp[((size_t)c * 64 + n) * 8 + 4];
        float Bv[8] = {B0.x, B0.y, B0.z, B0.w, B1.x, B1.y, B1.z, B1.w};
        float Cv[8] = {C0.x, C0.y, C0.z, C0.w, C1.x, C1.y, C1.z, C1.w};
        #pragma unroll
        for (int li = 0; li < 8; ++li) {
            float dv = rdlane(dvl, li);
            float p  = rdlane(pl, li);
            s = fmaf(exp2f(dv * Aln), s, p * Bv[li]);
            rbuf[w][li][n] = s * Cv[li];
        }
        // same-wave reduce over n (no barrier: writes+reads within one wave)
        float acc = 0.f;
        #pragma unroll
        for (int j = 0; j < 8; ++j) acc += rbuf[w][rli][g * 8 + j];
        acc += __shfl_xor(acc, 1);
        acc += __shfl_xor(acc, 2);
        acc += __shfl_xor(acc, 4);
        float uv = __shfl(uvl, rli);   // lane-varying index: stays outside the guard
        if (g == 0) {
            y[(l0 + rli) * D_INN + d] = acc + uv * Dpv;
        }
    }
}

// ---------------- Kernel 3c-1: segment-boundary states for scan=1 ----------------
__global__ __launch_bounds__(256) void k_sin(const float* __restrict__ A,
        const float* __restrict__ Qbuf, const float* __restrict__ SDbuf,
        float* __restrict__ Sin) {
    const int t = threadIdx.x, w = t >> 6, n = t & 63;
    const int b = blockIdx.y;
    const int d = blockIdx.x * 4 + w;
    const float Aln = A[d * D_HID + n] * 1.44269504f;
    float s = 0.f;
    #pragma unroll
    for (int seg = 0; seg < SEG; ++seg) {
        if (seg > 0) Sin[(((size_t)b * SEG + seg) * D_INN + d) * 64 + n] = s;
        float sdk = SDbuf[((size_t)(2 + b) * SEG + seg) * D_INN + d];
        float Qk = Qbuf[(((size_t)(2 + b) * SEG + seg) * D_INN + d) * 64 + n];
        s = fmaf(exp2f(sdk * Aln), s, Qk);
    }
}

// ---------------- Kernel 3c-2: parallel mem correction ----------------
__global__ __launch_bounds__(256) void k_fix(const float* __restrict__ A,
        const float* __restrict__ Sin, const float* __restrict__ cumd,
        float* __restrict__ mem) {
    const int t = threadIdx.x, w = t >> 6, n = t & 63;
    const int k = 8 + blockIdx.y;
    const int b = blockIdx.z;
    const int d = blockIdx.x * 4 + w;
    const int seg = k >> 3;
    const float Aln = A[d * D_HID + n] * 1.44269504f;
    float cum = cumd[((size_t)b * 128 + k) * D_INN + d];
    float sv = Sin[(((size_t)b * SEG + seg) * D_INN + d) * 64 + n];
    float v = exp2f(cum * Aln) * sv;
    #pragma unroll
    for (int off = 32; off >= 1; off >>= 1) v += __shfl_xor(v, off);
    if (n == 0) mem[((size_t)b * 128 + k) * D_INN + d] += v;
}

// ---------------- Kernel 4: fused K, V, VWo per memory row ----------------
__global__ __launch_bounds__(128) void k_kvwo(const float* __restrict__ mem,
        const float* __restrict__ Wk, const float* __restrict__ bk,
        const float* __restrict__ Wv, const float* __restrict__ bv,
        const float* __restrict__ Wo,
        float* __restrict__ K, float* __restrict__ VWo) {
    __shared__ float mrow[256];
    __shared__ float vrow[128];
    const int k = blockIdx.x, b = blockIdx.y;
    const int t = threadIdx.x;
    const float* mr = mem + ((size_t)b * 128 + k) * D_INN;
    mrow[t] = mr[t];
    mrow[t + 128] = mr[t + 128];
    __syncthreads();
    float aK = bk[t], aV = bv[t];
    for (int dd = 0; dd < D_INN; dd++) {
        float m = mrow[dd];
        aK += m * Wk[dd * D_MEMM + t];
        aV += m * Wv[dd * D_MEMM + t];
    }
    K[((size_t)b * 128 + k) * D_MEMM + t] = aK;
    vrow[t] = aV;
    __syncthreads();
    float a0 = 0.f, a1 = 0.f;
    for (int m = 0; m < 128; ++m) {
        float vm = vrow[m];
        a0 += vm * Wo[(size_t)m * D_INN + t];
        a1 += vm * Wo[(size_t)m * D_INN + t + 128];
    }
    VWo[((size_t)b * 128 + k) * D_INN + t] = a0;
    VWo[((size_t)b * 128 + k) * D_INN + t + 128] = a1;
}

// ---------------- Kernel 5: attention + epilogue, 16 rows per block ----------------
__global__ __launch_bounds__(256) void k_attn(const float* __restrict__ x,
        const float* __restrict__ proj, const float* __restrict__ y,
        const float* __restrict__ K, const float* __restrict__ VWo,
        const float* __restrict__ bo, float* __restrict__ out) {
    __shared__ float qs[16][132];
    __shared__ float ws[16][132];
    __shared__ float denom[16];
    const int t = threadIdx.x;
    const int b = blockIdx.y;
    const int r0 = blockIdx.x * 16;
    const size_t rowbase = (size_t)b * LL + r0;
    {
        int r = t >> 4, c8 = (t & 15) * 8;
        const float* src = &proj[(rowbase + r) * NTOT + NPROJ + c8];
        *(float4*)&qs[r][c8] = *(const float4*)src;
        *(float4*)&qs[r][c8 + 4] = *(const float4*)(src + 4);
    }
    __syncthreads();
    {
        const int k = t & 127, rg = (t >> 7) * 8;
        const float* Kr = K + ((size_t)b * 128 + k) * D_MEMM;
        float acc[8] = {};
        #pragma unroll 8
        for (int m = 0; m < 128; m += 4) {
            float4 kv = *(const float4*)&Kr[m];
            #pragma unroll
            for (int r = 0; r < 8; ++r) {
                float4 qv = *(const float4*)&qs[rg + r][m];
                acc[r] += qv.x * kv.x + qv.y * kv.y + qv.z * kv.z + qv.w * kv.w;
            }
        }
        #pragma unroll
        for (int r = 0; r < 8; ++r) ws[rg + r][k] = acc[r] * 0.125f;
    }
    __syncthreads();
    {
        const int r = t >> 4, j = t & 15;
        float4 v0 = *(float4*)&ws[r][j * 8];
        float4 v1 = *(float4*)&ws[r][j * 8 + 4];
        float mx = fmaxf(fmaxf(fmaxf(v0.x, v0.y), fmaxf(v0.z, v0.w)),
                         fmaxf(fmaxf(v1.x, v1.y), fmaxf(v1.z, v1.w)));
        #pragma unroll
        for (int o = 1; o < 16; o <<= 1) mx = fmaxf(mx, __shfl_xor(mx, o));
        v0.x = expf(v0.x - mx); v0.y = expf(v0.y - mx);
        v0.z = expf(v0.z - mx); v0.w = expf(v0.w - mx);
        v1.x = expf(v1.x - mx); v1.y = expf(v1.y - mx);
        v1.z = expf(v1.z - mx); v1.w = expf(v1.w - mx);
        float sum = v0.x + v0.y + v0.z + v0.w + v1.x + v1.y + v1.z + v1.w;
        #pragma unroll
        for (int o = 1; o < 16; o <<= 1) sum += __shfl_xor(sum, o);
        *(float4*)&ws[r][j * 8] = v0;
        *(float4*)&ws[r][j * 8 + 4] = v1;
        if (j == 0) denom[r] = sum;
    }
    __syncthreads();
    {
        const int w = t >> 6, lane = t & 63;
        const int c0 = lane * 4;
        const float* vb = VWo + (size_t)b * 128 * D_INN + c0;
        float acc[4][4] = {};
        #pragma unroll 8
        for (int k = 0; k < 128; k += 4) {
            float4 wv[4];
            #pragma unroll
            for (int r = 0; r < 4; ++r) wv[r] = *(float4*)&ws[w * 4 + r][k];
            #pragma unroll
            for (int kk = 0; kk < 4; ++kk) {
                float4 vw = *(const float4*)&vb[(size_t)(k + kk) * D_INN];
                #pragma unroll
                for (int r = 0; r < 4; ++r) {
                    float wk = (kk == 0 ? wv[r].x : kk == 1 ? wv[r].y : kk == 2 ? wv[r].z : wv[r].w);
                    acc[r][0] += wk * vw.x; acc[r][1] += wk * vw.y;
                    acc[r][2] += wk * vw.z; acc[r][3] += wk * vw.w;
                }
            }
        }
        float4 bov = *(const float4*)&bo[c0];
        #pragma unroll
        for (int r = 0; r < 4; ++r) {
            size_t rr = rowbase + w * 4 + r;
            float dn = 1.f / denom[w * 4 + r];
            float4 yv = *(const float4*)&y[rr * D_INN + c0];
            float4 xv = *(const float4*)&x[rr * D_INN + c0];
            float4 Ev = *(const float4*)&proj[rr * NTOT + 192 + c0];
            float4 Fv = *(const float4*)&proj[rr * NTOT + 448 + c0];
            float4 o;
            o.x = yv.x + (acc[r][0] * dn + bov.x) * Ev.x + xv.x * Fv.x;
            o.y = yv.y + (acc[r][1] * dn + bov.y) * Ev.y + xv.y * Fv.y;
            o.z = yv.z + (acc[r][2] * dn + bov.z) * Ev.z + xv.z * Fv.z;
            o.w = yv.w + (acc[r][3] * dn + bov.w) * Ev.w + xv.w * Fv.w;
            *(float4*)&out[rr * D_INN + c0] = o;
        }
    }
}

extern "C" void kernel_launch(void* const* d_in, const int* in_sizes, int n_in,
                              void* d_out, int out_size, void* d_ws, size_t ws_size,
                              hipStream_t stream) {
    const float* x    = (const float*)d_in[0];
    const float* Wx   = (const float*)d_in[1];
    const float* Wdt  = (const float*)d_in[2];
    const float* bdt  = (const float*)d_in[3];
    const float* Wdtl = (const float*)d_in[4];
    const float* bdtl = (const float*)d_in[5];
    const float* A    = (const float*)d_in[6];
    const float* Dp   = (const float*)d_in[7];
    const float* Wq   = (const float*)d_in[8];
    const float* bq   = (const float*)d_in[9];
    const float* Wk   = (const float*)d_in[10];
    const float* bk   = (const float*)d_in[11];
    const float* Wv   = (const float*)d_in[12];
    const float* bv   = (const float*)d_in[13];
    const float* Wo   = (const float*)d_in[14];
    const float* bo   = (const float*)d_in[15];
    float* out = (float*)d_out;
    float* ws = (float*)d_ws;

    float* proj    = ws;                                    // 4096*864
    float* deltaT  = proj + (size_t)NROWS * NTOT;           // [b][d][l]
    float* deltalT = deltaT + (size_t)NROWS * D_INN;        // [b][d][l]
    float* yb      = deltalT + (size_t)NROWS * D_INN;       // 4096*256
    float* mem     = yb + (size_t)NROWS * D_INN;            // 2*128*256
    float* Kb      = mem + (size_t)BB * 128 * D_INN;        // 2*128*128
    float* Qbuf    = Kb + (size_t)BB * 128 * D_MEMM;        // 4*16*256*64
    float* SDbuf   = Qbuf + (size_t)4 * SEG * D_INN * 64;   // 4*16*256
    float* cumd    = SDbuf + (size_t)4 * SEG * D_INN;       // 2*16*8*256
    float* Sin     = cumd + (size_t)BB * SEG * 8 * D_INN;   // 2*16*256*64
    float* VWo     = Sin + (size_t)BB * SEG * D_INN * 64;   // 2*128*256
    float* xT      = VWo + (size_t)BB * 128 * D_INN;        // [b][d][l]
    float* packed  = xT + (size_t)NROWS * D_INN;            // 3*2*256*64*8

    hipLaunchKernelGGL(k_gemm, dim3(14, 64), dim3(256), 0, stream, x, Wx, Wq, bq, proj, packed);
    hipLaunchKernelGGL(k_xt, dim3(32, 4, 2), dim3(256), 0, stream, x, xT);
    hipLaunchKernelGGL(k_delta, dim3(NROWS / 16), dim3(256), 0, stream,
                       proj, Wdt, bdt, Wdtl, bdtl, deltaT, deltalT);
    hipLaunchKernelGGL(k_scan1t<0>, dim3(64, 2, 16), dim3(256), 0, stream,
                       xT, packed, A, deltaT, Qbuf, SDbuf, cumd, mem);
    hipLaunchKernelGGL(k_scan1t<1>, dim3(64, 2, 16), dim3(256), 0, stream,
                       xT, packed, A, deltalT, Qbuf, SDbuf, cumd, mem);
    hipLaunchKernelGGL(k_scan2, dim3(64, 2, 16), dim3(256), 0, stream,
                       xT, packed, A, Dp, deltaT, Qbuf, SDbuf, yb);
    hipLaunchKernelGGL(k_sin, dim3(64, 2), dim3(256), 0, stream,
                       A, Qbuf, SDbuf, Sin);
    hipLaunchKernelGGL(k_fix, dim3(64, 120, 2), dim3(256), 0, stream,
                       A, Sin, cumd, mem);
    hipLaunchKernelGGL(k_kvwo, dim3(128, 2), dim3(128), 0, stream,
                       mem, Wk, bk, Wv, bv, Wo, Kb, VWo);
    hipLaunchKernelGGL(k_attn, dim3(128, 2), dim3(256), 0, stream,
                       x, proj, yb, Kb, VWo, bo, out);
}

// Round 12
// 201.764 us; speedup vs baseline: 1.1055x; 1.1055x over previous
//
#include <hip/hip_runtime.h>
#include <math.h>

#define D_INN 256
#define D_HID 64
#define DTR 16
#define D_MEMM 128
#define BB 2
#define LL 2048
#define NROWS (BB*LL)   // 4096
#define NPROJ 736
#define NTOT 864        // 736 proj cols + 128 Q cols
#define SEG 16
#define SEGLEN (LL/SEG) // 128
#define NCHUNK (LL/8)   // 256 8-step chunks per batch

typedef __attribute__((ext_vector_type(8))) short short8v;
typedef __attribute__((ext_vector_type(4))) float float4v;

static __device__ __forceinline__ unsigned short f2bf(float f) {
    unsigned int u = __float_as_uint(f);
    u += 0x7fff + ((u >> 16) & 1);   // RNE
    return (unsigned short)(u >> 16);
}

static __device__ __forceinline__ float rdlane(float v, int l) {
    return __uint_as_float(__builtin_amdgcn_readlane(__float_as_uint(v), l));
}

// packed index: (((g*BB + b)*NCHUNK + chunk)*64 + n)*8 + li   (g: 0=B, 1=Bl, 2=C)
#define PK(g, b, chunk, n, li) (((((size_t)(g)*BB + (b)) * NCHUNK + (chunk)) * 64 + (n)) * 8 + (li))

// ---------------- Kernel 1: proj = x @ [W_xproj | W_Q] (+b_Q), bf16 MFMA ----------------
__global__ __launch_bounds__(256) void k_gemm(const float* __restrict__ x,
        const float* __restrict__ Wx, const float* __restrict__ Wq,
        const float* __restrict__ bq, float* __restrict__ proj,
        float* __restrict__ packed) {
    __shared__ unsigned short As[64][40];
    __shared__ unsigned short Bs[64][40];
    const int t = threadIdx.x;
    const int lane = t & 63, w = t >> 6;
    const int wr = w >> 1, wc = w & 1;
    const int row0 = blockIdx.y * 64, col0 = blockIdx.x * 64;

    float4v acc[2][2];
    #pragma unroll
    for (int i = 0; i < 2; i++)
        #pragma unroll
        for (int j = 0; j < 2; j++) acc[i][j] = (float4v)0.f;

    const int ar = t >> 2, akq = (t & 3) * 8;
    const int bk = t >> 3, bcq = (t & 7) * 8;

    for (int k0 = 0; k0 < D_INN; k0 += 32) {
        float4 a0 = *(const float4*)&x[(size_t)(row0 + ar) * D_INN + k0 + akq];
        float4 a1 = *(const float4*)&x[(size_t)(row0 + ar) * D_INN + k0 + akq + 4];
        float4 b0 = {}, b1 = {};
        int col = col0 + bcq;
        if (col + 8 <= NPROJ) {
            b0 = *(const float4*)&Wx[(size_t)(k0 + bk) * NPROJ + col];
            b1 = *(const float4*)&Wx[(size_t)(k0 + bk) * NPROJ + col + 4];
        } else if (col < NTOT) {
            b0 = *(const float4*)&Wq[(size_t)(k0 + bk) * D_MEMM + (col - NPROJ)];
            b1 = *(const float4*)&Wq[(size_t)(k0 + bk) * D_MEMM + (col - NPROJ) + 4];
        }
        __syncthreads();
        {
            unsigned short av[8] = { f2bf(a0.x), f2bf(a0.y), f2bf(a0.z), f2bf(a0.w),
                                     f2bf(a1.x), f2bf(a1.y), f2bf(a1.z), f2bf(a1.w) };
            *(short8v*)&As[ar][akq] = *(short8v*)av;
            Bs[bcq + 0][bk] = f2bf(b0.x); Bs[bcq + 1][bk] = f2bf(b0.y);
            Bs[bcq + 2][bk] = f2bf(b0.z); Bs[bcq + 3][bk] = f2bf(b0.w);
            Bs[bcq + 4][bk] = f2bf(b1.x); Bs[bcq + 5][bk] = f2bf(b1.y);
            Bs[bcq + 6][bk] = f2bf(b1.z); Bs[bcq + 7][bk] = f2bf(b1.w);
        }
        __syncthreads();
        short8v af[2], bf[2];
        const int fr = lane & 15, fk = (lane >> 4) * 8;
        af[0] = *(short8v*)&As[wr * 32 + fr][fk];
        af[1] = *(short8v*)&As[wr * 32 + 16 + fr][fk];
        bf[0] = *(short8v*)&Bs[wc * 32 + fr][fk];
        bf[1] = *(short8v*)&Bs[wc * 32 + 16 + fr][fk];
        #pragma unroll
        for (int i = 0; i < 2; i++)
            #pragma unroll
            for (int j = 0; j < 2; j++)
                acc[i][j] = __builtin_amdgcn_mfma_f32_16x16x32_bf16(af[i], bf[j], acc[i][j], 0, 0, 0);
    }
    #pragma unroll
    for (int i = 0; i < 2; i++)
        #pragma unroll
        for (int j = 0; j < 2; j++) {
            int cc = col0 + wc * 32 + j * 16 + (lane & 15);
            int rr0 = row0 + wr * 32 + i * 16 + (lane >> 4) * 4;
            if (cc < 192) {   // B / Bl / C -> packed layout
                int g = cc >> 6, n = cc & 63;
                int bb = rr0 >> 11, l = rr0 & (LL - 1);
                float4 pk = make_float4(acc[i][j][0], acc[i][j][1], acc[i][j][2], acc[i][j][3]);
                *(float4*)&packed[PK(g, bb, l >> 3, n, l & 7)] = pk;
            } else {
                #pragma unroll
                for (int e = 0; e < 4; e++) {
                    float v = acc[i][j][e];
                    if (cc >= NPROJ) v += bq[cc - NPROJ];
                    proj[(size_t)(rr0 + e) * NTOT + cc] = v;
                }
            }
        }
}

// ---------------- Kernel 1b: xT[b][d][l] = x[b][l][d] (64x64 LDS transpose) ----------------
__global__ __launch_bounds__(256) void k_xt(const float* __restrict__ x,
        float* __restrict__ xT) {
    __shared__ float tile[64][65];
    const int t = threadIdx.x;
    const int lt = blockIdx.x * 64, dt = blockIdx.y * 64, b = blockIdx.z;
    const int c = t & 63, rg = (t >> 6) * 16;
    #pragma unroll
    for (int j = 0; j < 16; ++j)
        tile[rg + j][c] = x[((size_t)b * LL + lt + rg + j) * D_INN + dt + c];
    __syncthreads();
    #pragma unroll
    for (int j = 0; j < 16; ++j)
        xT[((size_t)b * D_INN + dt + rg + j) * LL + lt + c] = tile[c][rg + j];
}

// ---------------- Kernel 2: delta / delta_l, transposed outputs [d][l] ----------------
__global__ __launch_bounds__(256) void k_delta(const float* __restrict__ proj,
        const float* __restrict__ Wdt, const float* __restrict__ bdt,
        const float* __restrict__ Wdtl, const float* __restrict__ bdtl,
        float* __restrict__ deltaT, float* __restrict__ deltalT) {
    __shared__ float sdt[16][17], sdtl[16][17];
    const int t = threadIdx.x;
    const int r0 = blockIdx.x * 16;
    const int b = r0 >> 11, l0 = r0 & (LL - 1);
    {
        int r = t >> 4, c = t & 15;
        sdt[r][c]  = proj[(size_t)(r0 + r) * NTOT + 704 + c];
        sdtl[r][c] = proj[(size_t)(r0 + r) * NTOT + 720 + c];
    }
    __syncthreads();
    float w1[DTR], w2[DTR];
    #pragma unroll
    for (int r = 0; r < DTR; r++) {
        w1[r] = Wdt[r * D_INN + t];
        w2[r] = Wdtl[r * D_INN + t];
    }
    const float b1 = bdt[t], b2 = bdtl[t];
    float o1[16], o2[16];
    #pragma unroll
    for (int row = 0; row < 16; ++row) {
        float a1 = b1, a2 = b2;
        #pragma unroll
        for (int r = 0; r < DTR; r++) {
            a1 += sdt[row][r] * w1[r];
            a2 += sdtl[row][r] * w2[r];
        }
        o1[row] = (a1 > 20.f) ? a1 : log1pf(expf(a1));
        o2[row] = (a2 > 20.f) ? a2 : log1pf(expf(a2));
    }
    float* p1 = &deltaT[((size_t)b * D_INN + t) * LL + l0];
    float* p2 = &deltalT[((size_t)b * D_INN + t) * LL + l0];
    #pragma unroll
    for (int j = 0; j < 16; j += 4) {
        *(float4*)&p1[j] = make_float4(o1[j], o1[j+1], o1[j+2], o1[j+3]);
        *(float4*)&p2[j] = make_float4(o2[j], o2[j+1], o2[j+2], o2[j+3]);
    }
}

// ---------------- Kernel 3a: pass 1, templated on scan; packed B; peeled checkpoint ----
template<int SCAN>
__global__ __launch_bounds__(256) void k_scan1t(const float* __restrict__ xT,
        const float* __restrict__ packed, const float* __restrict__ A,
        const float* __restrict__ dTall,
        float* __restrict__ Qbuf, float* __restrict__ SDbuf,
        float* __restrict__ cumd, float* __restrict__ mem) {
    const int t = threadIdx.x;
    const int w = t >> 6, n = t & 63;
    const int b = blockIdx.y, seg = blockIdx.z;
    const int d = blockIdx.x * 4 + w;
    const float* dT = dTall + ((size_t)b * D_INN + d) * LL + seg * SEGLEN;
    const float* uT = xT + ((size_t)b * D_INN + d) * LL + seg * SEGLEN;
    const float Aln = A[d * D_HID + n] * 1.44269504f;
    const int lr = n & 7;
    const float* Bp = packed + PK(SCAN, b, seg * 16, 0, 0);

    float s = 0.f, sd = 0.f;
    for (int c = 0; c < 16; ++c) {
        float dvl = dT[c * 8 + lr];
        float pl  = dvl * uT[c * 8 + lr];
        float4 B0 = *(const float4*)&Bp[((size_t)c * 64 + n) * 8];
        float4 B1 = *(const float4*)&Bp[((size_t)c * 64 + n) * 8 + 4];
        float Bv[8] = {B0.x, B0.y, B0.z, B0.w, B1.x, B1.y, B1.z, B1.w};
        {
            float dv = rdlane(dvl, 0), p = rdlane(pl, 0);
            s = fmaf(exp2f(dv * Aln), s, p * Bv[0]);
            sd += dv;
        }
        if (SCAN == 1 && (c & 1) == 0) {
            float v = s;
            #pragma unroll
            for (int off = 32; off >= 1; off >>= 1) v += __shfl_xor(v, off);
            if (n == 0) {
                int k = seg * 8 + (c >> 1);
                mem[((size_t)b * 128 + k) * D_INN + d] = v;
                cumd[(((size_t)b * SEG + seg) * 8 + (c >> 1)) * D_INN + d] = sd;
            }
        }
        #pragma unroll
        for (int li = 1; li < 8; ++li) {
            float dv = rdlane(dvl, li), p = rdlane(pl, li);
            s = fmaf(exp2f(dv * Aln), s, p * Bv[li]);
            sd += dv;
        }
    }
    Qbuf[((((size_t)SCAN * 2 + b) * SEG + seg) * D_INN + d) * 64 + n] = s;
    if (n == 0) SDbuf[(((size_t)SCAN * 2 + b) * SEG + seg) * D_INN + d] = sd;
}

// ---------------- Kernel 3b: pass 2 — scan 0 only, packed B/C ----------------
__global__ __launch_bounds__(256) void k_scan2(const float* __restrict__ xT,
        const float* __restrict__ packed, const float* __restrict__ A,
        const float* __restrict__ Dp, const float* __restrict__ deltaT,
        const float* __restrict__ Qbuf, const float* __restrict__ SDbuf,
        float* __restrict__ y) {
    __shared__ float rbuf[4][8][65];
    const int t = threadIdx.x;
    const int w = t >> 6, n = t & 63;
    const int b = blockIdx.y, seg = blockIdx.z;
    const int d = blockIdx.x * 4 + w;
    const size_t rowbase = (size_t)b * LL + (size_t)seg * SEGLEN;
    const float* dT = deltaT + ((size_t)b * D_INN + d) * LL + seg * SEGLEN;
    const float* uT = xT + ((size_t)b * D_INN + d) * LL + seg * SEGLEN;
    const float Aln = A[d * D_HID + n] * 1.44269504f;
    const float Dpv = Dp[d];
    const int lr = n & 7;
    const int rli = n >> 3, g = n & 7;
    const float* Bp = packed + PK(0, b, seg * 16, 0, 0);
    const float* Cp = packed + PK(2, b, seg * 16, 0, 0);

    float s = 0.f;
    for (int k = 0; k < seg; ++k) {
        float sdk = SDbuf[(((size_t)b * SEG + k) * D_INN + d)];
        float Qk = Qbuf[(((size_t)b * SEG + k) * D_INN + d) * 64 + n];
        s = fmaf(exp2f(sdk * Aln), s, Qk);
    }

    for (int c = 0; c < 16; ++c) {
        const size_t l0 = rowbase + c * 8;
        float dvl = dT[c * 8 + lr];
        float uvl = uT[c * 8 + lr];
        float pl = dvl * uvl;
        float4 B0 = *(const float4*)&Bp[((size_t)c * 64 + n) * 8];
        float4 B1 = *(const float4*)&Bp[((size_t)c * 64 + n) * 8 + 4];
        float4 C0 = *(const float4*)&Cp[((size_t)c * 64 + n) * 8];
        float4 C1 = *(const float4*)&Cp[((size_t)c * 64 + n) * 8 + 4];
        float Bv[8] = {B0.x, B0.y, B0.z, B0.w, B1.x, B1.y, B1.z, B1.w};
        float Cv[8] = {C0.x, C0.y, C0.z, C0.w, C1.x, C1.y, C1.z, C1.w};
        #pragma unroll
        for (int li = 0; li < 8; ++li) {
            float dv = rdlane(dvl, li);
            float p  = rdlane(pl, li);
            s = fmaf(exp2f(dv * Aln), s, p * Bv[li]);
            rbuf[w][li][n] = s * Cv[li];
        }
        float acc = 0.f;
        #pragma unroll
        for (int j = 0; j < 8; ++j) acc += rbuf[w][rli][g * 8 + j];
        acc += __shfl_xor(acc, 1);
        acc += __shfl_xor(acc, 2);
        acc += __shfl_xor(acc, 4);
        float uv = __shfl(uvl, rli);   // lane-varying index: stays outside the guard
        if (g == 0) {
            y[(l0 + rli) * D_INN + d] = acc + uv * Dpv;
        }
    }
}

// ---------------- Kernel 3c-1: segment-boundary states for scan=1 ----------------
__global__ __launch_bounds__(256) void k_sin(const float* __restrict__ A,
        const float* __restrict__ Qbuf, const float* __restrict__ SDbuf,
        float* __restrict__ Sin) {
    const int t = threadIdx.x, w = t >> 6, n = t & 63;
    const int b = blockIdx.y;
    const int d = blockIdx.x * 4 + w;
    const float Aln = A[d * D_HID + n] * 1.44269504f;
    float s = 0.f;
    #pragma unroll
    for (int seg = 0; seg < SEG; ++seg) {
        if (seg > 0) Sin[(((size_t)b * SEG + seg) * D_INN + d) * 64 + n] = s;
        float sdk = SDbuf[((size_t)(2 + b) * SEG + seg) * D_INN + d];
        float Qk = Qbuf[(((size_t)(2 + b) * SEG + seg) * D_INN + d) * 64 + n];
        s = fmaf(exp2f(sdk * Aln), s, Qk);
    }
}

// ---------------- Kernel 3c-2: parallel mem correction ----------------
__global__ __launch_bounds__(256) void k_fix(const float* __restrict__ A,
        const float* __restrict__ Sin, const float* __restrict__ cumd,
        float* __restrict__ mem) {
    const int t = threadIdx.x, w = t >> 6, n = t & 63;
    const int k = 8 + blockIdx.y;
    const int b = blockIdx.z;
    const int d = blockIdx.x * 4 + w;
    const int seg = k >> 3;
    const float Aln = A[d * D_HID + n] * 1.44269504f;
    float cum = cumd[((size_t)b * 128 + k) * D_INN + d];
    float sv = Sin[(((size_t)b * SEG + seg) * D_INN + d) * 64 + n];
    float v = exp2f(cum * Aln) * sv;
    #pragma unroll
    for (int off = 32; off >= 1; off >>= 1) v += __shfl_xor(v, off);
    if (n == 0) mem[((size_t)b * 128 + k) * D_INN + d] += v;
}

// ---------------- Kernel 4: fused K^T, V, VWo per memory row ----------------
// KT layout [b][m][key] so attn QK reads are lane-coalesced over key.
__global__ __launch_bounds__(128) void k_kvwo(const float* __restrict__ mem,
        const float* __restrict__ Wk, const float* __restrict__ bk,
        const float* __restrict__ Wv, const float* __restrict__ bv,
        const float* __restrict__ Wo,
        float* __restrict__ KT, float* __restrict__ VWo) {
    __shared__ float mrow[256];
    __shared__ float vrow[128];
    const int k = blockIdx.x, b = blockIdx.y;
    const int t = threadIdx.x;
    const float* mr = mem + ((size_t)b * 128 + k) * D_INN;
    mrow[t] = mr[t];
    mrow[t + 128] = mr[t + 128];
    __syncthreads();
    float aK = bk[t], aV = bv[t];
    for (int dd = 0; dd < D_INN; dd++) {
        float m = mrow[dd];
        aK += m * Wk[dd * D_MEMM + t];
        aV += m * Wv[dd * D_MEMM + t];
    }
    KT[((size_t)b * 128 + t) * 128 + k] = aK;   // transposed store
    vrow[t] = aV;
    __syncthreads();
    float a0 = 0.f, a1 = 0.f;
    for (int m = 0; m < 128; ++m) {
        float vm = vrow[m];
        a0 += vm * Wo[(size_t)m * D_INN + t];
        a1 += vm * Wo[(size_t)m * D_INN + t + 128];
    }
    VWo[((size_t)b * 128 + k) * D_INN + t] = a0;
    VWo[((size_t)b * 128 + k) * D_INN + t + 128] = a1;
}

// ---------------- Kernel 5: attention + epilogue, 8 rows per block, coalesced KT ----
__global__ __launch_bounds__(256) void k_attn(const float* __restrict__ x,
        const float* __restrict__ proj, const float* __restrict__ y,
        const float* __restrict__ KT, const float* __restrict__ VWo,
        const float* __restrict__ bo, float* __restrict__ out) {
    __shared__ float qs[8][132];
    __shared__ float ws[8][132];
    __shared__ float denom[8];
    const int t = threadIdx.x;
    const int b = blockIdx.y;
    const int r0 = blockIdx.x * 8;
    const size_t rowbase = (size_t)b * LL + r0;
    {   // stage q: 8 rows x 128, float4 per thread
        int r = t >> 5, c4 = (t & 31) * 4;
        *(float4*)&qs[r][c4] = *(const float4*)&proj[(rowbase + r) * NTOT + NPROJ + c4];
    }
    __syncthreads();
    {   // QK^T: thread -> key kk (lane-coalesced KT), 4 rows
        const int kk = t & 127, rg = (t >> 7) * 4;
        const float* KTb = KT + (size_t)b * 128 * 128 + kk;
        float acc[4] = {};
        #pragma unroll 8
        for (int m = 0; m < 128; m += 4) {
            float k0 = KTb[(size_t)m * 128];
            float k1 = KTb[(size_t)(m + 1) * 128];
            float k2 = KTb[(size_t)(m + 2) * 128];
            float k3 = KTb[(size_t)(m + 3) * 128];
            #pragma unroll
            for (int r = 0; r < 4; ++r) {
                float4 qv = *(const float4*)&qs[rg + r][m];
                acc[r] += qv.x * k0 + qv.y * k1 + qv.z * k2 + qv.w * k3;
            }
        }
        #pragma unroll
        for (int r = 0; r < 4; ++r) ws[rg + r][kk] = acc[r] * 0.125f;
    }
    __syncthreads();
    {   // softmax: row r = t>>5, 32 lanes per row, 4 keys per lane
        const int r = t >> 5, j = t & 31;
        float4 v0 = *(float4*)&ws[r][j * 4];
        float mx = fmaxf(fmaxf(v0.x, v0.y), fmaxf(v0.z, v0.w));
        #pragma unroll
        for (int o = 1; o < 32; o <<= 1) mx = fmaxf(mx, __shfl_xor(mx, o));
        v0.x = expf(v0.x - mx); v0.y = expf(v0.y - mx);
        v0.z = expf(v0.z - mx); v0.w = expf(v0.w - mx);
        float sum = v0.x + v0.y + v0.z + v0.w;
        #pragma unroll
        for (int o = 1; o < 32; o <<= 1) sum += __shfl_xor(sum, o);
        *(float4*)&ws[r][j * 4] = v0;
        if (j == 0) denom[r] = sum;
    }
    __syncthreads();
    {   // w @ VWo: wave -> 2 rows, lane -> 4 cols; fused epilogue
        const int w = t >> 6, lane = t & 63;
        const int c0 = lane * 4;
        const float* vb = VWo + (size_t)b * 128 * D_INN + c0;
        float acc[2][4] = {};
        #pragma unroll 8
        for (int k = 0; k < 128; k += 2) {
            float4 vw0 = *(const float4*)&vb[(size_t)k * D_INN];
            float4 vw1 = *(const float4*)&vb[(size_t)(k + 1) * D_INN];
            #pragma unroll
            for (int r = 0; r < 2; ++r) {
                float wk0 = ws[w * 2 + r][k];
                float wk1 = ws[w * 2 + r][k + 1];
                acc[r][0] += wk0 * vw0.x + wk1 * vw1.x;
                acc[r][1] += wk0 * vw0.y + wk1 * vw1.y;
                acc[r][2] += wk0 * vw0.z + wk1 * vw1.z;
                acc[r][3] += wk0 * vw0.w + wk1 * vw1.w;
            }
        }
        float4 bov = *(const float4*)&bo[c0];
        #pragma unroll
        for (int r = 0; r < 2; ++r) {
            size_t rr = rowbase + w * 2 + r;
            float dn = 1.f / denom[w * 2 + r];
            float4 yv = *(const float4*)&y[rr * D_INN + c0];
            float4 xv = *(const float4*)&x[rr * D_INN + c0];
            float4 Ev = *(const float4*)&proj[rr * NTOT + 192 + c0];
            float4 Fv = *(const float4*)&proj[rr * NTOT + 448 + c0];
            float4 o;
            o.x = yv.x + (acc[r][0] * dn + bov.x) * Ev.x + xv.x * Fv.x;
            o.y = yv.y + (acc[r][1] * dn + bov.y) * Ev.y + xv.y * Fv.y;
            o.z = yv.z + (acc[r][2] * dn + bov.z) * Ev.z + xv.z * Fv.z;
            o.w = yv.w + (acc[r][3] * dn + bov.w) * Ev.w + xv.w * Fv.w;
            *(float4*)&out[rr * D_INN + c0] = o;
        }
    }
}

extern "C" void kernel_launch(void* const* d_in, const int* in_sizes, int n_in,
                              void* d_out, int out_size, void* d_ws, size_t ws_size,
                              hipStream_t stream) {
    const float* x    = (const float*)d_in[0];
    const float* Wx   = (const float*)d_in[1];
    const float* Wdt  = (const float*)d_in[2];
    const float* bdt  = (const float*)d_in[3];
    const float* Wdtl = (const float*)d_in[4];
    const float* bdtl = (const float*)d_in[5];
    const float* A    = (const float*)d_in[6];
    const float* Dp   = (const float*)d_in[7];
    const float* Wq   = (const float*)d_in[8];
    const float* bq   = (const float*)d_in[9];
    const float* Wk   = (const float*)d_in[10];
    const float* bk   = (const float*)d_in[11];
    const float* Wv   = (const float*)d_in[12];
    const float* bv   = (const float*)d_in[13];
    const float* Wo   = (const float*)d_in[14];
    const float* bo   = (const float*)d_in[15];
    float* out = (float*)d_out;
    float* ws = (float*)d_ws;

    float* proj    = ws;                                    // 4096*864
    float* deltaT  = proj + (size_t)NROWS * NTOT;           // [b][d][l]
    float* deltalT = deltaT + (size_t)NROWS * D_INN;        // [b][d][l]
    float* yb      = deltalT + (size_t)NROWS * D_INN;       // 4096*256
    float* mem     = yb + (size_t)NROWS * D_INN;            // 2*128*256
    float* KTb     = mem + (size_t)BB * 128 * D_INN;        // 2*128*128 (transposed)
    float* Qbuf    = KTb + (size_t)BB * 128 * D_MEMM;       // 4*16*256*64
    float* SDbuf   = Qbuf + (size_t)4 * SEG * D_INN * 64;   // 4*16*256
    float* cumd    = SDbuf + (size_t)4 * SEG * D_INN;       // 2*16*8*256
    float* Sin     = cumd + (size_t)BB * SEG * 8 * D_INN;   // 2*16*256*64
    float* VWo     = Sin + (size_t)BB * SEG * D_INN * 64;   // 2*128*256
    float* xT      = VWo + (size_t)BB * 128 * D_INN;        // [b][d][l]
    float* packed  = xT + (size_t)NROWS * D_INN;            // 3*2*256*64*8

    hipLaunchKernelGGL(k_gemm, dim3(14, 64), dim3(256), 0, stream, x, Wx, Wq, bq, proj, packed);
    hipLaunchKernelGGL(k_xt, dim3(32, 4, 2), dim3(256), 0, stream, x, xT);
    hipLaunchKernelGGL(k_delta, dim3(NROWS / 16), dim3(256), 0, stream,
                       proj, Wdt, bdt, Wdtl, bdtl, deltaT, deltalT);
    hipLaunchKernelGGL(k_scan1t<0>, dim3(64, 2, 16), dim3(256), 0, stream,
                       xT, packed, A, deltaT, Qbuf, SDbuf, cumd, mem);
    hipLaunchKernelGGL(k_scan1t<1>, dim3(64, 2, 16), dim3(256), 0, stream,
                       xT, packed, A, deltalT, Qbuf, SDbuf, cumd, mem);
    hipLaunchKernelGGL(k_scan2, dim3(64, 2, 16), dim3(256), 0, stream,
                       xT, packed, A, Dp, deltaT, Qbuf, SDbuf, yb);
    hipLaunchKernelGGL(k_sin, dim3(64, 2), dim3(256), 0, stream,
                       A, Qbuf, SDbuf, Sin);
    hipLaunchKernelGGL(k_fix, dim3(64, 120, 2), dim3(256), 0, stream,
                       A, Sin, cumd, mem);
    hipLaunchKernelGGL(k_kvwo, dim3(128, 2), dim3(128), 0, stream,
                       mem, Wk, bk, Wv, bv, Wo, KTb, VWo);
    hipLaunchKernelGGL(k_attn, dim3(LL / 8, 2), dim3(256), 0, stream,
                       x, proj, yb, KTb, VWo, bo, out);
}

// Round 14
// 195.208 us; speedup vs baseline: 1.1426x; 1.0336x over previous
//
#include <hip/hip_runtime.h>
#include <math.h>

#define D_INN 256
#define D_HID 64
#define DTR 16
#define D_MEMM 128
#define BB 2
#define LL 2048
#define NROWS (BB*LL)   // 4096
#define NPROJ 736
#define NTOT 864        // 736 proj cols + 128 Q cols
#define SEG 16
#define SEGLEN (LL/SEG) // 128
#define NCHUNK (LL/8)   // 256 8-step chunks per batch

typedef __attribute__((ext_vector_type(8))) short short8v;
typedef __attribute__((ext_vector_type(4))) float float4v;

static __device__ __forceinline__ unsigned short f2bf(float f) {
    unsigned int u = __float_as_uint(f);
    u += 0x7fff + ((u >> 16) & 1);   // RNE
    return (unsigned short)(u >> 16);
}

static __device__ __forceinline__ float rdlane(float v, int l) {
    return __uint_as_float(__builtin_amdgcn_readlane(__float_as_uint(v), l));
}

// packed index: (((g*BB + b)*NCHUNK + chunk)*64 + n)*8 + li   (g: 0=B, 1=Bl, 2=C)
#define PK(g, b, chunk, n, li) (((((size_t)(g)*BB + (b)) * NCHUNK + (chunk)) * 64 + (n)) * 8 + (li))

// ---------------- Kernel 1: proj = x @ [W_xproj | W_Q] (+b_Q), bf16 MFMA ----------------
__global__ __launch_bounds__(256) void k_gemm(const float* __restrict__ x,
        const float* __restrict__ Wx, const float* __restrict__ Wq,
        const float* __restrict__ bq, float* __restrict__ proj,
        float* __restrict__ packed) {
    __shared__ unsigned short As[64][40];
    __shared__ unsigned short Bs[64][40];
    const int t = threadIdx.x;
    const int lane = t & 63, w = t >> 6;
    const int wr = w >> 1, wc = w & 1;
    const int row0 = blockIdx.y * 64, col0 = blockIdx.x * 64;

    float4v acc[2][2];
    #pragma unroll
    for (int i = 0; i < 2; i++)
        #pragma unroll
        for (int j = 0; j < 2; j++) acc[i][j] = (float4v)0.f;

    const int ar = t >> 2, akq = (t & 3) * 8;
    const int bk = t >> 3, bcq = (t & 7) * 8;

    for (int k0 = 0; k0 < D_INN; k0 += 32) {
        float4 a0 = *(const float4*)&x[(size_t)(row0 + ar) * D_INN + k0 + akq];
        float4 a1 = *(const float4*)&x[(size_t)(row0 + ar) * D_INN + k0 + akq + 4];
        float4 b0 = {}, b1 = {};
        int col = col0 + bcq;
        if (col + 8 <= NPROJ) {
            b0 = *(const float4*)&Wx[(size_t)(k0 + bk) * NPROJ + col];
            b1 = *(const float4*)&Wx[(size_t)(k0 + bk) * NPROJ + col + 4];
        } else if (col < NTOT) {
            b0 = *(const float4*)&Wq[(size_t)(k0 + bk) * D_MEMM + (col - NPROJ)];
            b1 = *(const float4*)&Wq[(size_t)(k0 + bk) * D_MEMM + (col - NPROJ) + 4];
        }
        __syncthreads();
        {
            unsigned short av[8] = { f2bf(a0.x), f2bf(a0.y), f2bf(a0.z), f2bf(a0.w),
                                     f2bf(a1.x), f2bf(a1.y), f2bf(a1.z), f2bf(a1.w) };
            *(short8v*)&As[ar][akq] = *(short8v*)av;
            Bs[bcq + 0][bk] = f2bf(b0.x); Bs[bcq + 1][bk] = f2bf(b0.y);
            Bs[bcq + 2][bk] = f2bf(b0.z); Bs[bcq + 3][bk] = f2bf(b0.w);
            Bs[bcq + 4][bk] = f2bf(b1.x); Bs[bcq + 5][bk] = f2bf(b1.y);
            Bs[bcq + 6][bk] = f2bf(b1.z); Bs[bcq + 7][bk] = f2bf(b1.w);
        }
        __syncthreads();
        short8v af[2], bf[2];
        const int fr = lane & 15, fk = (lane >> 4) * 8;
        af[0] = *(short8v*)&As[wr * 32 + fr][fk];
        af[1] = *(short8v*)&As[wr * 32 + 16 + fr][fk];
        bf[0] = *(short8v*)&Bs[wc * 32 + fr][fk];
        bf[1] = *(short8v*)&Bs[wc * 32 + 16 + fr][fk];
        #pragma unroll
        for (int i = 0; i < 2; i++)
            #pragma unroll
            for (int j = 0; j < 2; j++)
                acc[i][j] = __builtin_amdgcn_mfma_f32_16x16x32_bf16(af[i], bf[j], acc[i][j], 0, 0, 0);
    }
    #pragma unroll
    for (int i = 0; i < 2; i++)
        #pragma unroll
        for (int j = 0; j < 2; j++) {
            int cc = col0 + wc * 32 + j * 16 + (lane & 15);
            int rr0 = row0 + wr * 32 + i * 16 + (lane >> 4) * 4;
            if (cc < 192) {   // B / Bl / C -> packed layout
                int g = cc >> 6, n = cc & 63;
                int bb = rr0 >> 11, l = rr0 & (LL - 1);
                float4 pk = make_float4(acc[i][j][0], acc[i][j][1], acc[i][j][2], acc[i][j][3]);
                *(float4*)&packed[PK(g, bb, l >> 3, n, l & 7)] = pk;
            } else {
                #pragma unroll
                for (int e = 0; e < 4; e++) {
                    float v = acc[i][j][e];
                    if (cc >= NPROJ) v += bq[cc - NPROJ];
                    proj[(size_t)(rr0 + e) * NTOT + cc] = v;
                }
            }
        }
}

// ---------------- Kernel 2: prep = {delta transposed | x transpose} ----------------
__global__ __launch_bounds__(256) void k_prep(const float* __restrict__ x,
        const float* __restrict__ proj,
        const float* __restrict__ Wdt, const float* __restrict__ bdt,
        const float* __restrict__ Wdtl, const float* __restrict__ bdtl,
        float* __restrict__ deltaT, float* __restrict__ deltalT,
        float* __restrict__ xT) {
    __shared__ float sh[64 * 66];
    const int t = threadIdx.x;
    if (blockIdx.y == 0) {
        float (*sdt)[17]  = (float(*)[17])sh;
        float (*sdtl)[17] = (float(*)[17])(sh + 16 * 17);
        const int r0 = blockIdx.x * 16;
        const int b = r0 >> 11, l0 = r0 & (LL - 1);
        {
            int r = t >> 4, c = t & 15;
            sdt[r][c]  = proj[(size_t)(r0 + r) * NTOT + 704 + c];
            sdtl[r][c] = proj[(size_t)(r0 + r) * NTOT + 720 + c];
        }
        __syncthreads();
        float w1[DTR], w2[DTR];
        #pragma unroll
        for (int r = 0; r < DTR; r++) {
            w1[r] = Wdt[r * D_INN + t];
            w2[r] = Wdtl[r * D_INN + t];
        }
        const float b1 = bdt[t], b2 = bdtl[t];
        float o1[16], o2[16];
        #pragma unroll
        for (int row = 0; row < 16; ++row) {
            float a1 = b1, a2 = b2;
            #pragma unroll
            for (int r = 0; r < DTR; r++) {
                a1 += sdt[row][r] * w1[r];
                a2 += sdtl[row][r] * w2[r];
            }
            o1[row] = (a1 > 20.f) ? a1 : log1pf(expf(a1));
            o2[row] = (a2 > 20.f) ? a2 : log1pf(expf(a2));
        }
        float* p1 = &deltaT[((size_t)b * D_INN + t) * LL + l0];
        float* p2 = &deltalT[((size_t)b * D_INN + t) * LL + l0];
        #pragma unroll
        for (int j = 0; j < 16; j += 4) {
            *(float4*)&p1[j] = make_float4(o1[j], o1[j+1], o1[j+2], o1[j+3]);
            *(float4*)&p2[j] = make_float4(o2[j], o2[j+1], o2[j+2], o2[j+3]);
        }
    } else {
        float (*tile)[65] = (float(*)[65])sh;
        const int bx = blockIdx.x;
        const int lt = (bx & 31) * 64, dt = ((bx >> 5) & 3) * 64, b = bx >> 7;
        const int c = t & 63, rg = (t >> 6) * 16;
        #pragma unroll
        for (int j = 0; j < 16; ++j)
            tile[rg + j][c] = x[((size_t)b * LL + lt + rg + j) * D_INN + dt + c];
        __syncthreads();
        #pragma unroll
        for (int j = 0; j < 16; ++j)
            xT[((size_t)b * D_INN + dt + rg + j) * LL + lt + c] = tile[c][rg + j];
    }
}

// ---------------- scan device helpers ----------------
template<bool CK>
static __device__ __forceinline__ void seg_pass1(
        const float* __restrict__ dT, const float* __restrict__ uT,
        const float* __restrict__ Bp, float Aln, int lr, int n,
        float& sOut, float& sdOut, float* cum, float* part) {
    float s = 0.f, sd = 0.f;
    #pragma unroll
    for (int c = 0; c < 16; ++c) {
        float dvl = dT[c * 8 + lr];
        float pl  = dvl * uT[c * 8 + lr];
        float4 B0 = *(const float4*)&Bp[((size_t)c * 64 + n) * 8];
        float4 B1 = *(const float4*)&Bp[((size_t)c * 64 + n) * 8 + 4];
        float Bv[8] = {B0.x, B0.y, B0.z, B0.w, B1.x, B1.y, B1.z, B1.w};
        {
            float dv = rdlane(dvl, 0), p = rdlane(pl, 0);
            s = fmaf(exp2f(dv * Aln), s, p * Bv[0]);
            sd += dv;
        }
        if (CK && (c & 1) == 0) {
            float v = s;
            #pragma unroll
            for (int off = 32; off >= 1; off >>= 1) v += __shfl_xor(v, off);
            part[c >> 1] = v;    // reduced value present in all lanes
            cum[c >> 1] = sd;    // sd is lane-uniform (readlane broadcasts)
        }
        #pragma unroll
        for (int li = 1; li < 8; ++li) {
            float dv = rdlane(dvl, li), p = rdlane(pl, li);
            s = fmaf(exp2f(dv * Aln), s, p * Bv[li]);
            sd += dv;
        }
    }
    sOut = s; sdOut = sd;
}

// ---------------- Kernel 3A: both scans' pass 1, fused (shares uT loads) ----------------
// grid (64, 2, 16); block 256 = 4 waves; wave w -> d = d0+w, lane n.
__global__ __launch_bounds__(256) void k_scanA(const float* __restrict__ xT,
        const float* __restrict__ packed, const float* __restrict__ A,
        const float* __restrict__ deltaT, const float* __restrict__ deltalT,
        float* __restrict__ Qbuf, float* __restrict__ SDbuf,
        float* __restrict__ cumd, float* __restrict__ mem) {
    const int t = threadIdx.x, w = t >> 6, n = t & 63;
    const int b = blockIdx.y, seg = blockIdx.z;
    const int d = blockIdx.x * 4 + w;
    const int lr = n & 7;
    const float Aln = A[d * D_HID + n] * 1.44269504f;
    const float* uT  = xT + ((size_t)b * D_INN + d) * LL + seg * SEGLEN;
    const float* dT0 = deltaT + ((size_t)b * D_INN + d) * LL + seg * SEGLEN;
    const float* dT1 = deltalT + ((size_t)b * D_INN + d) * LL + seg * SEGLEN;

    float cum[8], part[8];
    float q0, sd0, q1, sd1;
    seg_pass1<false>(dT0, uT, packed + PK(0, b, seg * 16, 0, 0), Aln, lr, n,
                     q0, sd0, nullptr, nullptr);
    seg_pass1<true>(dT1, uT, packed + PK(1, b, seg * 16, 0, 0), Aln, lr, n,
                    q1, sd1, cum, part);

    Qbuf[(((size_t)b * SEG + seg) * D_INN + d) * 64 + n] = q0;
    Qbuf[(((size_t)(2 + b) * SEG + seg) * D_INN + d) * 64 + n] = q1;
    if (n == 0) {
        SDbuf[((size_t)b * SEG + seg) * D_INN + d] = sd0;
        SDbuf[((size_t)(2 + b) * SEG + seg) * D_INN + d] = sd1;
        #pragma unroll
        for (int ck = 0; ck < 8; ++ck) {
            mem[((size_t)b * 128 + seg * 8 + ck) * D_INN + d] = part[ck];
            cumd[(((size_t)b * SEG + seg) * 8 + ck) * D_INN + d] = cum[ck];
        }
    }
}

// ---------------- Kernel 3B: prefix + pass 2 (scan0) + mem corrections (scan1) ----------
// grid (64, 2, 16); block 256 = 4 waves.
__global__ __launch_bounds__(256) void k_scanBC(const float* __restrict__ xT,
        const float* __restrict__ packed, const float* __restrict__ A,
        const float* __restrict__ Dp, const float* __restrict__ deltaT,
        const float* __restrict__ Qbuf, const float* __restrict__ SDbuf,
        const float* __restrict__ cumd,
        float* __restrict__ y, float* __restrict__ mem) {
    __shared__ float rbuf[4][8][65];
    const int t = threadIdx.x, w = t >> 6, n = t & 63;
    const int b = blockIdx.y, seg = blockIdx.z;
    const int d = blockIdx.x * 4 + w;
    const int lr = n & 7, rli = n >> 3, g = n & 7;
    const float Aln = A[d * D_HID + n] * 1.44269504f;
    const float Dpv = Dp[d];
    const size_t rowbase = (size_t)b * LL + (size_t)seg * SEGLEN;
    const float* uT  = xT + ((size_t)b * D_INN + d) * LL + seg * SEGLEN;
    const float* dT0 = deltaT + ((size_t)b * D_INN + d) * LL + seg * SEGLEN;
    const float* Bp = packed + PK(0, b, seg * 16, 0, 0);
    const float* Cp = packed + PK(2, b, seg * 16, 0, 0);

    // prefix s_in for both scans
    float sin0 = 0.f, sin1 = 0.f;
    for (int k = 0; k < seg; ++k) {
        float sdk0 = SDbuf[((size_t)b * SEG + k) * D_INN + d];
        float qk0  = Qbuf[(((size_t)b * SEG + k) * D_INN + d) * 64 + n];
        sin0 = fmaf(exp2f(sdk0 * Aln), sin0, qk0);
        float sdk1 = SDbuf[((size_t)(2 + b) * SEG + k) * D_INN + d];
        float qk1  = Qbuf[(((size_t)(2 + b) * SEG + k) * D_INN + d) * 64 + n];
        sin1 = fmaf(exp2f(sdk1 * Aln), sin1, qk1);
    }

    // mem corrections for scan1 (seg > 0)
    if (seg > 0) {
        #pragma unroll
        for (int ck = 0; ck < 8; ++ck) {
            float cum = cumd[(((size_t)b * SEG + seg) * 8 + ck) * D_INN + d];
            float v = exp2f(cum * Aln) * sin1;
            #pragma unroll
            for (int off = 32; off >= 1; off >>= 1) v += __shfl_xor(v, off);
            if (n == 0) mem[((size_t)b * 128 + seg * 8 + ck) * D_INN + d] += v;
        }
    }

    // pass 2 for scan0
    float s = sin0;
    for (int c = 0; c < 16; ++c) {
        const size_t l0 = rowbase + c * 8;
        float dvl = dT0[c * 8 + lr];
        float uvl = uT[c * 8 + lr];
        float pl = dvl * uvl;
        float4 B0 = *(const float4*)&Bp[((size_t)c * 64 + n) * 8];
        float4 B1 = *(const float4*)&Bp[((size_t)c * 64 + n) * 8 + 4];
        float4 C0 = *(const float4*)&Cp[((size_t)c * 64 + n) * 8];
        float4 C1 = *(const float4*)&Cp[((size_t)c * 64 + n) * 8 + 4];
        float Bv[8] = {B0.x, B0.y, B0.z, B0.w, B1.x, B1.y, B1.z, B1.w};
        float Cv[8] = {C0.x, C0.y, C0.z, C0.w, C1.x, C1.y, C1.z, C1.w};
        #pragma unroll
        for (int li = 0; li < 8; ++li) {
            float dv = rdlane(dvl, li);
            float p  = rdlane(pl, li);
            s = fmaf(exp2f(dv * Aln), s, p * Bv[li]);
            rbuf[w][li][n] = s * Cv[li];
        }
        float acc = 0.f;
        #pragma unroll
        for (int j = 0; j < 8; ++j) acc += rbuf[w][rli][g * 8 + j];
        acc += __shfl_xor(acc, 1);
        acc += __shfl_xor(acc, 2);
        acc += __shfl_xor(acc, 4);
        float uv = __shfl(uvl, rli);   // outside the guard (all lanes active)
        if (g == 0) {
            y[(l0 + rli) * D_INN + d] = acc + uv * Dpv;
        }
    }
}

// ---------------- Kernel 4: fused K^T, V, VWo per memory row ----------------
__global__ __launch_bounds__(128) void k_kvwo(const float* __restrict__ mem,
        const float* __restrict__ Wk, const float* __restrict__ bk,
        const float* __restrict__ Wv, const float* __restrict__ bv,
        const float* __restrict__ Wo,
        float* __restrict__ KT, float* __restrict__ VWo) {
    __shared__ float mrow[256];
    __shared__ float vrow[128];
    const int k = blockIdx.x, b = blockIdx.y;
    const int t = threadIdx.x;
    const float* mr = mem + ((size_t)b * 128 + k) * D_INN;
    mrow[t] = mr[t];
    mrow[t + 128] = mr[t + 128];
    __syncthreads();
    float aK = bk[t], aV = bv[t];
    for (int dd = 0; dd < D_INN; dd++) {
        float m = mrow[dd];
        aK += m * Wk[dd * D_MEMM + t];
        aV += m * Wv[dd * D_MEMM + t];
    }
    KT[((size_t)b * 128 + t) * 128 + k] = aK;   // transposed store
    vrow[t] = aV;
    __syncthreads();
    float a0 = 0.f, a1 = 0.f;
    for (int m = 0; m < 128; ++m) {
        float vm = vrow[m];
        a0 += vm * Wo[(size_t)m * D_INN + t];
        a1 += vm * Wo[(size_t)m * D_INN + t + 128];
    }
    VWo[((size_t)b * 128 + k) * D_INN + t] = a0;
    VWo[((size_t)b * 128 + k) * D_INN + t + 128] = a1;
}

// ---------------- Kernel 5: attention + epilogue, 8 rows per block ----------------
__global__ __launch_bounds__(256) void k_attn(const float* __restrict__ x,
        const float* __restrict__ proj, const float* __restrict__ y,
        const float* __restrict__ KT, const float* __restrict__ VWo,
        const float* __restrict__ bo, float* __restrict__ out) {
    __shared__ float qs[8][132];
    __shared__ float ws[8][132];
    __shared__ float denom[8];
    const int t = threadIdx.x;
    const int b = blockIdx.y;
    const int r0 = blockIdx.x * 8;
    const size_t rowbase = (size_t)b * LL + r0;
    {
        int r = t >> 5, c4 = (t & 31) * 4;
        *(float4*)&qs[r][c4] = *(const float4*)&proj[(rowbase + r) * NTOT + NPROJ + c4];
    }
    __syncthreads();
    {
        const int kk = t & 127, rg = (t >> 7) * 4;
        const float* KTb = KT + (size_t)b * 128 * 128 + kk;
        float acc[4] = {};
        #pragma unroll 8
        for (int m = 0; m < 128; m += 4) {
            float k0 = KTb[(size_t)m * 128];
            float k1 = KTb[(size_t)(m + 1) * 128];
            float k2 = KTb[(size_t)(m + 2) * 128];
            float k3 = KTb[(size_t)(m + 3) * 128];
            #pragma unroll
            for (int r = 0; r < 4; ++r) {
                float4 qv = *(const float4*)&qs[rg + r][m];
                acc[r] += qv.x * k0 + qv.y * k1 + qv.z * k2 + qv.w * k3;
            }
        }
        #pragma unroll
        for (int r = 0; r < 4; ++r) ws[rg + r][kk] = acc[r] * 0.125f;
    }
    __syncthreads();
    {
        const int r = t >> 5, j = t & 31;
        float4 v0 = *(float4*)&ws[r][j * 4];
        float mx = fmaxf(fmaxf(v0.x, v0.y), fmaxf(v0.z, v0.w));
        #pragma unroll
        for (int o = 1; o < 32; o <<= 1) mx = fmaxf(mx, __shfl_xor(mx, o));
        v0.x = expf(v0.x - mx); v0.y = expf(v0.y - mx);
        v0.z = expf(v0.z - mx); v0.w = expf(v0.w - mx);
        float sum = v0.x + v0.y + v0.z + v0.w;
        #pragma unroll
        for (int o = 1; o < 32; o <<= 1) sum += __shfl_xor(sum, o);
        *(float4*)&ws[r][j * 4] = v0;
        if (j == 0) denom[r] = sum;
    }
    __syncthreads();
    {
        const int w = t >> 6, lane = t & 63;
        const int c0 = lane * 4;
        const float* vb = VWo + (size_t)b * 128 * D_INN + c0;
        float acc[2][4] = {};
        #pragma unroll 8
        for (int k = 0; k < 128; k += 2) {
            float4 vw0 = *(const float4*)&vb[(size_t)k * D_INN];
            float4 vw1 = *(const float4*)&vb[(size_t)(k + 1) * D_INN];
            #pragma unroll
            for (int r = 0; r < 2; ++r) {
                float wk0 = ws[w * 2 + r][k];
                float wk1 = ws[w * 2 + r][k + 1];
                acc[r][0] += wk0 * vw0.x + wk1 * vw1.x;
                acc[r][1] += wk0 * vw0.y + wk1 * vw1.y;
                acc[r][2] += wk0 * vw0.z + wk1 * vw1.z;
                acc[r][3] += wk0 * vw0.w + wk1 * vw1.w;
            }
        }
        float4 bov = *(const float4*)&bo[c0];
        #pragma unroll
        for (int r = 0; r < 2; ++r) {
            size_t rr = rowbase + w * 2 + r;
            float dn = 1.f / denom[w * 2 + r];
            float4 yv = *(const float4*)&y[rr * D_INN + c0];
            float4 xv = *(const float4*)&x[rr * D_INN + c0];
            float4 Ev = *(const float4*)&proj[rr * NTOT + 192 + c0];
            float4 Fv = *(const float4*)&proj[rr * NTOT + 448 + c0];
            float4 o;
            o.x = yv.x + (acc[r][0] * dn + bov.x) * Ev.x + xv.x * Fv.x;
            o.y = yv.y + (acc[r][1] * dn + bov.y) * Ev.y + xv.y * Fv.y;
            o.z = yv.z + (acc[r][2] * dn + bov.z) * Ev.z + xv.z * Fv.z;
            o.w = yv.w + (acc[r][3] * dn + bov.w) * Ev.w + xv.w * Fv.w;
            *(float4*)&out[rr * D_INN + c0] = o;
        }
    }
}

extern "C" void kernel_launch(void* const* d_in, const int* in_sizes, int n_in,
                              void* d_out, int out_size, void* d_ws, size_t ws_size,
                              hipStream_t stream) {
    const float* x    = (const float*)d_in[0];
    const float* Wx   = (const float*)d_in[1];
    const float* Wdt  = (const float*)d_in[2];
    const float* bdt  = (const float*)d_in[3];
    const float* Wdtl = (const float*)d_in[4];
    const float* bdtl = (const float*)d_in[5];
    const float* A    = (const float*)d_in[6];
    const float* Dp   = (const float*)d_in[7];
    const float* Wq   = (const float*)d_in[8];
    const float* bq   = (const float*)d_in[9];
    const float* Wk   = (const float*)d_in[10];
    const float* bk   = (const float*)d_in[11];
    const float* Wv   = (const float*)d_in[12];
    const float* bv   = (const float*)d_in[13];
    const float* Wo   = (const float*)d_in[14];
    const float* bo   = (const float*)d_in[15];
    float* out = (float*)d_out;
    float* ws = (float*)d_ws;

    float* proj    = ws;                                    // 4096*864
    float* deltaT  = proj + (size_t)NROWS * NTOT;           // [b][d][l]
    float* deltalT = deltaT + (size_t)NROWS * D_INN;        // [b][d][l]
    float* yb      = deltalT + (size_t)NROWS * D_INN;       // 4096*256
    float* mem     = yb + (size_t)NROWS * D_INN;            // 2*128*256
    float* KTb     = mem + (size_t)BB * 128 * D_INN;        // 2*128*128 (transposed)
    float* Qbuf    = KTb + (size_t)BB * 128 * D_MEMM;       // 4*16*256*64
    float* SDbuf   = Qbuf + (size_t)4 * SEG * D_INN * 64;   // 4*16*256
    float* cumd    = SDbuf + (size_t)4 * SEG * D_INN;       // 2*16*8*256
    float* VWo     = cumd + (size_t)BB * SEG * 8 * D_INN;   // 2*128*256
    float* xT      = VWo + (size_t)BB * 128 * D_INN;        // [b][d][l]
    float* packed  = xT + (size_t)NROWS * D_INN;            // 3*2*256*64*8

    hipLaunchKernelGGL(k_gemm, dim3(14, 64), dim3(256), 0, stream, x, Wx, Wq, bq, proj, packed);
    hipLaunchKernelGGL(k_prep, dim3(256, 2), dim3(256), 0, stream,
                       x, proj, Wdt, bdt, Wdtl, bdtl, deltaT, deltalT, xT);
    hipLaunchKernelGGL(k_scanA, dim3(64, 2, 16), dim3(256), 0, stream,
                       xT, packed, A, deltaT, deltalT, Qbuf, SDbuf, cumd, mem);
    hipLaunchKernelGGL(k_scanBC, dim3(64, 2, 16), dim3(256), 0, stream,
                       xT, packed, A, Dp, deltaT, Qbuf, SDbuf, cumd, yb, mem);
    hipLaunchKernelGGL(k_kvwo, dim3(128, 2), dim3(128), 0, stream,
                       mem, Wk, bk, Wv, bv, Wo, KTb, VWo);
    hipLaunchKernelGGL(k_attn, dim3(LL / 8, 2), dim3(256), 0, stream,
                       x, proj, yb, KTb, VWo, bo, out);
}

// Round 15
// 192.120 us; speedup vs baseline: 1.1609x; 1.0161x over previous
//
#include <hip/hip_runtime.h>
#include <math.h>

#define D_INN 256
#define D_HID 64
#define DTR 16
#define D_MEMM 128
#define BB 2
#define LL 2048
#define NROWS (BB*LL)   // 4096
#define NPROJ 736
#define NTOT 864        // 736 proj cols + 128 Q cols
#define SEG 16
#define SEGLEN (LL/SEG) // 128
#define NCHUNK (LL/8)   // 256 8-step chunks per batch

typedef __attribute__((ext_vector_type(8))) short short8v;
typedef __attribute__((ext_vector_type(4))) float float4v;
typedef __attribute__((ext_vector_type(2))) float float2v;

static __device__ __forceinline__ unsigned short f2bf(float f) {
    unsigned int u = __float_as_uint(f);
    u += 0x7fff + ((u >> 16) & 1);   // RNE
    return (unsigned short)(u >> 16);
}

static __device__ __forceinline__ float rdlane(float v, int l) {
    return __uint_as_float(__builtin_amdgcn_readlane(__float_as_uint(v), l));
}

// packed fp32 (VOP3P): 2 results per 2-cycle issue
static __device__ __forceinline__ float2v pk_fma(float2v a, float2v b, float2v c) {
    float2v d;
    asm("v_pk_fma_f32 %0, %1, %2, %3" : "=v"(d) : "v"(a), "v"(b), "v"(c));
    return d;
}
static __device__ __forceinline__ float2v pk_mul(float2v a, float2v b) {
    float2v d;
    asm("v_pk_mul_f32 %0, %1, %2" : "=v"(d) : "v"(a), "v"(b));
    return d;
}
static __device__ __forceinline__ float2v pk_add(float2v a, float2v b) {
    float2v d;
    asm("v_pk_add_f32 %0, %1, %2" : "=v"(d) : "v"(a), "v"(b));
    return d;
}

// packed index: (((g*BB + b)*NCHUNK + chunk)*64 + n)*8 + li   (g: 0=B, 1=Bl, 2=C)
#define PK(g, b, chunk, n, li) (((((size_t)(g)*BB + (b)) * NCHUNK + (chunk)) * 64 + (n)) * 8 + (li))

// ---------------- Kernel 1: proj = x @ [W_xproj | W_Q] (+b_Q), bf16 MFMA ----------------
__global__ __launch_bounds__(256) void k_gemm(const float* __restrict__ x,
        const float* __restrict__ Wx, const float* __restrict__ Wq,
        const float* __restrict__ bq, float* __restrict__ proj,
        float* __restrict__ packed) {
    __shared__ unsigned short As[64][40];
    __shared__ unsigned short Bs[64][40];
    const int t = threadIdx.x;
    const int lane = t & 63, w = t >> 6;
    const int wr = w >> 1, wc = w & 1;
    const int row0 = blockIdx.y * 64, col0 = blockIdx.x * 64;

    float4v acc[2][2];
    #pragma unroll
    for (int i = 0; i < 2; i++)
        #pragma unroll
        for (int j = 0; j < 2; j++) acc[i][j] = (float4v)0.f;

    const int ar = t >> 2, akq = (t & 3) * 8;
    const int bk = t >> 3, bcq = (t & 7) * 8;

    for (int k0 = 0; k0 < D_INN; k0 += 32) {
        float4 a0 = *(const float4*)&x[(size_t)(row0 + ar) * D_INN + k0 + akq];
        float4 a1 = *(const float4*)&x[(size_t)(row0 + ar) * D_INN + k0 + akq + 4];
        float4 b0 = {}, b1 = {};
        int col = col0 + bcq;
        if (col + 8 <= NPROJ) {
            b0 = *(const float4*)&Wx[(size_t)(k0 + bk) * NPROJ + col];
            b1 = *(const float4*)&Wx[(size_t)(k0 + bk) * NPROJ + col + 4];
        } else if (col < NTOT) {
            b0 = *(const float4*)&Wq[(size_t)(k0 + bk) * D_MEMM + (col - NPROJ)];
            b1 = *(const float4*)&Wq[(size_t)(k0 + bk) * D_MEMM + (col - NPROJ) + 4];
        }
        __syncthreads();
        {
            unsigned short av[8] = { f2bf(a0.x), f2bf(a0.y), f2bf(a0.z), f2bf(a0.w),
                                     f2bf(a1.x), f2bf(a1.y), f2bf(a1.z), f2bf(a1.w) };
            *(short8v*)&As[ar][akq] = *(short8v*)av;
            Bs[bcq + 0][bk] = f2bf(b0.x); Bs[bcq + 1][bk] = f2bf(b0.y);
            Bs[bcq + 2][bk] = f2bf(b0.z); Bs[bcq + 3][bk] = f2bf(b0.w);
            Bs[bcq + 4][bk] = f2bf(b1.x); Bs[bcq + 5][bk] = f2bf(b1.y);
            Bs[bcq + 6][bk] = f2bf(b1.z); Bs[bcq + 7][bk] = f2bf(b1.w);
        }
        __syncthreads();
        short8v af[2], bf[2];
        const int fr = lane & 15, fk = (lane >> 4) * 8;
        af[0] = *(short8v*)&As[wr * 32 + fr][fk];
        af[1] = *(short8v*)&As[wr * 32 + 16 + fr][fk];
        bf[0] = *(short8v*)&Bs[wc * 32 + fr][fk];
        bf[1] = *(short8v*)&Bs[wc * 32 + 16 + fr][fk];
        #pragma unroll
        for (int i = 0; i < 2; i++)
            #pragma unroll
            for (int j = 0; j < 2; j++)
                acc[i][j] = __builtin_amdgcn_mfma_f32_16x16x32_bf16(af[i], bf[j], acc[i][j], 0, 0, 0);
    }
    #pragma unroll
    for (int i = 0; i < 2; i++)
        #pragma unroll
        for (int j = 0; j < 2; j++) {
            int cc = col0 + wc * 32 + j * 16 + (lane & 15);
            int rr0 = row0 + wr * 32 + i * 16 + (lane >> 4) * 4;
            if (cc < 192) {   // B / Bl / C -> packed layout
                int g = cc >> 6, n = cc & 63;
                int bb = rr0 >> 11, l = rr0 & (LL - 1);
                float4 pk = make_float4(acc[i][j][0], acc[i][j][1], acc[i][j][2], acc[i][j][3]);
                *(float4*)&packed[PK(g, bb, l >> 3, n, l & 7)] = pk;
            } else {
                #pragma unroll
                for (int e = 0; e < 4; e++) {
                    float v = acc[i][j][e];
                    if (cc >= NPROJ) v += bq[cc - NPROJ];
                    proj[(size_t)(rr0 + e) * NTOT + cc] = v;
                }
            }
        }
}

// ---------------- Kernel 2: prep = {delta transposed | x transpose} ----------------
__global__ __launch_bounds__(256) void k_prep(const float* __restrict__ x,
        const float* __restrict__ proj,
        const float* __restrict__ Wdt, const float* __restrict__ bdt,
        const float* __restrict__ Wdtl, const float* __restrict__ bdtl,
        float* __restrict__ deltaT, float* __restrict__ deltalT,
        float* __restrict__ xT) {
    __shared__ float sh[64 * 66];
    const int t = threadIdx.x;
    if (blockIdx.y == 0) {
        float (*sdt)[17]  = (float(*)[17])sh;
        float (*sdtl)[17] = (float(*)[17])(sh + 16 * 17);
        const int r0 = blockIdx.x * 16;
        const int b = r0 >> 11, l0 = r0 & (LL - 1);
        {
            int r = t >> 4, c = t & 15;
            sdt[r][c]  = proj[(size_t)(r0 + r) * NTOT + 704 + c];
            sdtl[r][c] = proj[(size_t)(r0 + r) * NTOT + 720 + c];
        }
        __syncthreads();
        float w1[DTR], w2[DTR];
        #pragma unroll
        for (int r = 0; r < DTR; r++) {
            w1[r] = Wdt[r * D_INN + t];
            w2[r] = Wdtl[r * D_INN + t];
        }
        const float b1 = bdt[t], b2 = bdtl[t];
        float o1[16], o2[16];
        #pragma unroll
        for (int row = 0; row < 16; ++row) {
            float a1 = b1, a2 = b2;
            #pragma unroll
            for (int r = 0; r < DTR; r++) {
                a1 += sdt[row][r] * w1[r];
                a2 += sdtl[row][r] * w2[r];
            }
            o1[row] = (a1 > 20.f) ? a1 : log1pf(expf(a1));
            o2[row] = (a2 > 20.f) ? a2 : log1pf(expf(a2));
        }
        float* p1 = &deltaT[((size_t)b * D_INN + t) * LL + l0];
        float* p2 = &deltalT[((size_t)b * D_INN + t) * LL + l0];
        #pragma unroll
        for (int j = 0; j < 16; j += 4) {
            *(float4*)&p1[j] = make_float4(o1[j], o1[j+1], o1[j+2], o1[j+3]);
            *(float4*)&p2[j] = make_float4(o2[j], o2[j+1], o2[j+2], o2[j+3]);
        }
    } else {
        float (*tile)[65] = (float(*)[65])sh;
        const int bx = blockIdx.x;
        const int lt = (bx & 31) * 64, dt = ((bx >> 5) & 3) * 64, b = bx >> 7;
        const int c = t & 63, rg = (t >> 6) * 16;
        #pragma unroll
        for (int j = 0; j < 16; ++j)
            tile[rg + j][c] = x[((size_t)b * LL + lt + rg + j) * D_INN + dt + c];
        __syncthreads();
        #pragma unroll
        for (int j = 0; j < 16; ++j)
            xT[((size_t)b * D_INN + dt + rg + j) * LL + lt + c] = tile[c][rg + j];
    }
}

// ---------------- Kernel 3A: both scans' pass 1, packed-f32 dual recurrence ----------------
// grid (64, 2, 16); block 256 = 4 waves; wave w -> d = d0+w, lane n.
__global__ __launch_bounds__(256) void k_scanA(const float* __restrict__ xT,
        const float* __restrict__ packed, const float* __restrict__ A,
        const float* __restrict__ deltaT, const float* __restrict__ deltalT,
        float* __restrict__ Qbuf, float* __restrict__ SDbuf,
        float* __restrict__ cumd, float* __restrict__ mem) {
    const int t = threadIdx.x, w = t >> 6, n = t & 63;
    const int b = blockIdx.y, seg = blockIdx.z;
    const int d = blockIdx.x * 4 + w;
    const int lr = n & 7;
    const float Aln = A[d * D_HID + n] * 1.44269504f;
    const float2v Aln2 = {Aln, Aln};
    const float* uT  = xT + ((size_t)b * D_INN + d) * LL + seg * SEGLEN;
    const float* dT0 = deltaT + ((size_t)b * D_INN + d) * LL + seg * SEGLEN;
    const float* dT1 = deltalT + ((size_t)b * D_INN + d) * LL + seg * SEGLEN;
    const float* Bp0 = packed + PK(0, b, seg * 16, 0, 0);
    const float* Bp1 = packed + PK(1, b, seg * 16, 0, 0);

    float cum[8], part[8];
    float2v s01 = {0.f, 0.f}, sd01 = {0.f, 0.f};

    for (int c = 0; c < 16; ++c) {
        float u   = uT[c * 8 + lr];
        float dv0 = dT0[c * 8 + lr];
        float dv1 = dT1[c * 8 + lr];
        float pl0 = dv0 * u, pl1 = dv1 * u;
        float4 B00 = *(const float4*)&Bp0[((size_t)c * 64 + n) * 8];
        float4 B01 = *(const float4*)&Bp0[((size_t)c * 64 + n) * 8 + 4];
        float4 B10 = *(const float4*)&Bp1[((size_t)c * 64 + n) * 8];
        float4 B11 = *(const float4*)&Bp1[((size_t)c * 64 + n) * 8 + 4];
        float Bv0[8] = {B00.x, B00.y, B00.z, B00.w, B01.x, B01.y, B01.z, B01.w};
        float Bv1[8] = {B10.x, B10.y, B10.z, B10.w, B11.x, B11.y, B11.z, B11.w};

        float2v dv01[8], dA01[8], pB01[8];
        #pragma unroll
        for (int li = 0; li < 8; ++li) {
            dv01[li] = (float2v){rdlane(dv0, li), rdlane(dv1, li)};
            float2v m = pk_mul(dv01[li], Aln2);
            dA01[li] = (float2v){exp2f(m.x), exp2f(m.y)};
            float2v p = (float2v){rdlane(pl0, li), rdlane(pl1, li)};
            pB01[li] = pk_mul(p, (float2v){Bv0[li], Bv1[li]});
        }
        #pragma unroll
        for (int li = 0; li < 8; ++li) {
            s01 = pk_fma(dA01[li], s01, pB01[li]);
            sd01 = pk_add(sd01, dv01[li]);
            if (li == 0 && (c & 1) == 0) {
                float v = s01.y;
                #pragma unroll
                for (int off = 32; off >= 1; off >>= 1) v += __shfl_xor(v, off);
                part[c >> 1] = v;
                cum[c >> 1] = sd01.y;
            }
        }
    }

    Qbuf[(((size_t)b * SEG + seg) * D_INN + d) * 64 + n] = s01.x;
    Qbuf[(((size_t)(2 + b) * SEG + seg) * D_INN + d) * 64 + n] = s01.y;
    if (n == 0) {
        SDbuf[((size_t)b * SEG + seg) * D_INN + d] = sd01.x;
        SDbuf[((size_t)(2 + b) * SEG + seg) * D_INN + d] = sd01.y;
        #pragma unroll
        for (int ck = 0; ck < 8; ++ck) {
            mem[((size_t)b * 128 + seg * 8 + ck) * D_INN + d] = part[ck];
            cumd[(((size_t)b * SEG + seg) * 8 + ck) * D_INN + d] = cum[ck];
        }
    }
}

// ---------------- Kernel 3B: prefix + pass 2 (scan0) + mem corrections (scan1) ----------
__global__ __launch_bounds__(256) void k_scanBC(const float* __restrict__ xT,
        const float* __restrict__ packed, const float* __restrict__ A,
        const float* __restrict__ Dp, const float* __restrict__ deltaT,
        const float* __restrict__ Qbuf, const float* __restrict__ SDbuf,
        const float* __restrict__ cumd,
        float* __restrict__ y, float* __restrict__ mem) {
    __shared__ float rbuf[4][8][65];
    const int t = threadIdx.x, w = t >> 6, n = t & 63;
    const int b = blockIdx.y, seg = blockIdx.z;
    const int d = blockIdx.x * 4 + w;
    const int lr = n & 7, rli = n >> 3, g = n & 7;
    const float Aln = A[d * D_HID + n] * 1.44269504f;
    const float Dpv = Dp[d];
    const size_t rowbase = (size_t)b * LL + (size_t)seg * SEGLEN;
    const float* uT  = xT + ((size_t)b * D_INN + d) * LL + seg * SEGLEN;
    const float* dT0 = deltaT + ((size_t)b * D_INN + d) * LL + seg * SEGLEN;
    const float* Bp = packed + PK(0, b, seg * 16, 0, 0);
    const float* Cp = packed + PK(2, b, seg * 16, 0, 0);

    // prefix s_in for both scans
    float sin0 = 0.f, sin1 = 0.f;
    for (int k = 0; k < seg; ++k) {
        float sdk0 = SDbuf[((size_t)b * SEG + k) * D_INN + d];
        float qk0  = Qbuf[(((size_t)b * SEG + k) * D_INN + d) * 64 + n];
        sin0 = fmaf(exp2f(sdk0 * Aln), sin0, qk0);
        float sdk1 = SDbuf[((size_t)(2 + b) * SEG + k) * D_INN + d];
        float qk1  = Qbuf[(((size_t)(2 + b) * SEG + k) * D_INN + d) * 64 + n];
        sin1 = fmaf(exp2f(sdk1 * Aln), sin1, qk1);
    }

    // mem corrections for scan1 (seg > 0)
    if (seg > 0) {
        #pragma unroll
        for (int ck = 0; ck < 8; ++ck) {
            float cum = cumd[(((size_t)b * SEG + seg) * 8 + ck) * D_INN + d];
            float v = exp2f(cum * Aln) * sin1;
            #pragma unroll
            for (int off = 32; off >= 1; off >>= 1) v += __shfl_xor(v, off);
            if (n == 0) mem[((size_t)b * 128 + seg * 8 + ck) * D_INN + d] += v;
        }
    }

    // pass 2 for scan0 (ILP: precompute dA / pB before the serial chain)
    float s = sin0;
    for (int c = 0; c < 16; ++c) {
        const size_t l0 = rowbase + c * 8;
        float dvl = dT0[c * 8 + lr];
        float uvl = uT[c * 8 + lr];
        float pl = dvl * uvl;
        float4 B0 = *(const float4*)&Bp[((size_t)c * 64 + n) * 8];
        float4 B1 = *(const float4*)&Bp[((size_t)c * 64 + n) * 8 + 4];
        float4 C0 = *(const float4*)&Cp[((size_t)c * 64 + n) * 8];
        float4 C1 = *(const float4*)&Cp[((size_t)c * 64 + n) * 8 + 4];
        float Bv[8] = {B0.x, B0.y, B0.z, B0.w, B1.x, B1.y, B1.z, B1.w};
        float Cv[8] = {C0.x, C0.y, C0.z, C0.w, C1.x, C1.y, C1.z, C1.w};
        float dAr[8], pBr[8];
        #pragma unroll
        for (int li = 0; li < 8; ++li) {
            dAr[li] = exp2f(rdlane(dvl, li) * Aln);
            pBr[li] = rdlane(pl, li) * Bv[li];
        }
        #pragma unroll
        for (int li = 0; li < 8; ++li) {
            s = fmaf(dAr[li], s, pBr[li]);
            rbuf[w][li][n] = s * Cv[li];
        }
        float acc = 0.f;
        #pragma unroll
        for (int j = 0; j < 8; ++j) acc += rbuf[w][rli][g * 8 + j];
        acc += __shfl_xor(acc, 1);
        acc += __shfl_xor(acc, 2);
        acc += __shfl_xor(acc, 4);
        float uv = __shfl(uvl, rli);   // outside the guard (all lanes active)
        if (g == 0) {
            y[(l0 + rli) * D_INN + d] = acc + uv * Dpv;
        }
    }
}

// ---------------- Kernel 4: fused K^T, V, VWo per memory row ----------------
__global__ __launch_bounds__(128) void k_kvwo(const float* __restrict__ mem,
        const float* __restrict__ Wk, const float* __restrict__ bk,
        const float* __restrict__ Wv, const float* __restrict__ bv,
        const float* __restrict__ Wo,
        float* __restrict__ KT, float* __restrict__ VWo) {
    __shared__ float mrow[256];
    __shared__ float vrow[128];
    const int k = blockIdx.x, b = blockIdx.y;
    const int t = threadIdx.x;
    const float* mr = mem + ((size_t)b * 128 + k) * D_INN;
    mrow[t] = mr[t];
    mrow[t + 128] = mr[t + 128];
    __syncthreads();
    float aK = bk[t], aV = bv[t];
    for (int dd = 0; dd < D_INN; dd++) {
        float m = mrow[dd];
        aK += m * Wk[dd * D_MEMM + t];
        aV += m * Wv[dd * D_MEMM + t];
    }
    KT[((size_t)b * 128 + t) * 128 + k] = aK;   // transposed store
    vrow[t] = aV;
    __syncthreads();
    float a0 = 0.f, a1 = 0.f;
    for (int m = 0; m < 128; ++m) {
        float vm = vrow[m];
        a0 += vm * Wo[(size_t)m * D_INN + t];
        a1 += vm * Wo[(size_t)m * D_INN + t + 128];
    }
    VWo[((size_t)b * 128 + k) * D_INN + t] = a0;
    VWo[((size_t)b * 128 + k) * D_INN + t + 128] = a1;
}

// ---------------- Kernel 5: attention + epilogue, 8 rows per block ----------------
__global__ __launch_bounds__(256) void k_attn(const float* __restrict__ x,
        const float* __restrict__ proj, const float* __restrict__ y,
        const float* __restrict__ KT, const float* __restrict__ VWo,
        const float* __restrict__ bo, float* __restrict__ out) {
    __shared__ float qs[8][132];
    __shared__ float ws[8][132];
    __shared__ float denom[8];
    const int t = threadIdx.x;
    const int b = blockIdx.y;
    const int r0 = blockIdx.x * 8;
    const size_t rowbase = (size_t)b * LL + r0;
    {
        int r = t >> 5, c4 = (t & 31) * 4;
        *(float4*)&qs[r][c4] = *(const float4*)&proj[(rowbase + r) * NTOT + NPROJ + c4];
    }
    __syncthreads();
    {
        const int kk = t & 127, rg = (t >> 7) * 4;
        const float* KTb = KT + (size_t)b * 128 * 128 + kk;
        float acc[4] = {};
        #pragma unroll 8
        for (int m = 0; m < 128; m += 4) {
            float k0 = KTb[(size_t)m * 128];
            float k1 = KTb[(size_t)(m + 1) * 128];
            float k2 = KTb[(size_t)(m + 2) * 128];
            float k3 = KTb[(size_t)(m + 3) * 128];
            #pragma unroll
            for (int r = 0; r < 4; ++r) {
                float4 qv = *(const float4*)&qs[rg + r][m];
                acc[r] += qv.x * k0 + qv.y * k1 + qv.z * k2 + qv.w * k3;
            }
        }
        #pragma unroll
        for (int r = 0; r < 4; ++r) ws[rg + r][kk] = acc[r] * 0.125f;
    }
    __syncthreads();
    {
        const int r = t >> 5, j = t & 31;
        float4 v0 = *(float4*)&ws[r][j * 4];
        float mx = fmaxf(fmaxf(v0.x, v0.y), fmaxf(v0.z, v0.w));
        #pragma unroll
        for (int o = 1; o < 32; o <<= 1) mx = fmaxf(mx, __shfl_xor(mx, o));
        v0.x = expf(v0.x - mx); v0.y = expf(v0.y - mx);
        v0.z = expf(v0.z - mx); v0.w = expf(v0.w - mx);
        float sum = v0.x + v0.y + v0.z + v0.w;
        #pragma unroll
        for (int o = 1; o < 32; o <<= 1) sum += __shfl_xor(sum, o);
        *(float4*)&ws[r][j * 4] = v0;
        if (j == 0) denom[r] = sum;
    }
    __syncthreads();
    {
        const int w = t >> 6, lane = t & 63;
        const int c0 = lane * 4;
        const float* vb = VWo + (size_t)b * 128 * D_INN + c0;
        float acc[2][4] = {};
        #pragma unroll 8
        for (int k = 0; k < 128; k += 2) {
            float4 vw0 = *(const float4*)&vb[(size_t)k * D_INN];
            float4 vw1 = *(const float4*)&vb[(size_t)(k + 1) * D_INN];
            #pragma unroll
            for (int r = 0; r < 2; ++r) {
                float wk0 = ws[w * 2 + r][k];
                float wk1 = ws[w * 2 + r][k + 1];
                acc[r][0] += wk0 * vw0.x + wk1 * vw1.x;
                acc[r][1] += wk0 * vw0.y + wk1 * vw1.y;
                acc[r][2] += wk0 * vw0.z + wk1 * vw1.z;
                acc[r][3] += wk0 * vw0.w + wk1 * vw1.w;
            }
        }
        float4 bov = *(const float4*)&bo[c0];
        #pragma unroll
        for (int r = 0; r < 2; ++r) {
            size_t rr = rowbase + w * 2 + r;
            float dn = 1.f / denom[w * 2 + r];
            float4 yv = *(const float4*)&y[rr * D_INN + c0];
            float4 xv = *(const float4*)&x[rr * D_INN + c0];
            float4 Ev = *(const float4*)&proj[rr * NTOT + 192 + c0];
            float4 Fv = *(const float4*)&proj[rr * NTOT + 448 + c0];
            float4 o;
            o.x = yv.x + (acc[r][0] * dn + bov.x) * Ev.x + xv.x * Fv.x;
            o.y = yv.y + (acc[r][1] * dn + bov.y) * Ev.y + xv.y * Fv.y;
            o.z = yv.z + (acc[r][2] * dn + bov.z) * Ev.z + xv.z * Fv.z;
            o.w = yv.w + (acc[r][3] * dn + bov.w) * Ev.w + xv.w * Fv.w;
            *(float4*)&out[rr * D_INN + c0] = o;
        }
    }
}

extern "C" void kernel_launch(void* const* d_in, const int* in_sizes, int n_in,
                              void* d_out, int out_size, void* d_ws, size_t ws_size,
                              hipStream_t stream) {
    const float* x    = (const float*)d_in[0];
    const float* Wx   = (const float*)d_in[1];
    const float* Wdt  = (const float*)d_in[2];
    const float* bdt  = (const float*)d_in[3];
    const float* Wdtl = (const float*)d_in[4];
    const float* bdtl = (const float*)d_in[5];
    const float* A    = (const float*)d_in[6];
    const float* Dp   = (const float*)d_in[7];
    const float* Wq   = (const float*)d_in[8];
    const float* bq   = (const float*)d_in[9];
    const float* Wk   = (const float*)d_in[10];
    const float* bk   = (const float*)d_in[11];
    const float* Wv   = (const float*)d_in[12];
    const float* bv   = (const float*)d_in[13];
    const float* Wo   = (const float*)d_in[14];
    const float* bo   = (const float*)d_in[15];
    float* out = (float*)d_out;
    float* ws = (float*)d_ws;

    float* proj    = ws;                                    // 4096*864
    float* deltaT  = proj + (size_t)NROWS * NTOT;           // [b][d][l]
    float* deltalT = deltaT + (size_t)NROWS * D_INN;        // [b][d][l]
    float* yb      = deltalT + (size_t)NROWS * D_INN;       // 4096*256
    float* mem     = yb + (size_t)NROWS * D_INN;            // 2*128*256
    float* KTb     = mem + (size_t)BB * 128 * D_INN;        // 2*128*128 (transposed)
    float* Qbuf    = KTb + (size_t)BB * 128 * D_MEMM;       // 4*16*256*64
    float* SDbuf   = Qbuf + (size_t)4 * SEG * D_INN * 64;   // 4*16*256
    float* cumd    = SDbuf + (size_t)4 * SEG * D_INN;       // 2*16*8*256
    float* VWo     = cumd + (size_t)BB * SEG * 8 * D_INN;   // 2*128*256
    float* xT      = VWo + (size_t)BB * 128 * D_INN;        // [b][d][l]
    float* packed  = xT + (size_t)NROWS * D_INN;            // 3*2*256*64*8

    hipLaunchKernelGGL(k_gemm, dim3(14, 64), dim3(256), 0, stream, x, Wx, Wq, bq, proj, packed);
    hipLaunchKernelGGL(k_prep, dim3(256, 2), dim3(256), 0, stream,
                       x, proj, Wdt, bdt, Wdtl, bdtl, deltaT, deltalT, xT);
    hipLaunchKernelGGL(k_scanA, dim3(64, 2, 16), dim3(256), 0, stream,
                       xT, packed, A, deltaT, deltalT, Qbuf, SDbuf, cumd, mem);
    hipLaunchKernelGGL(k_scanBC, dim3(64, 2, 16), dim3(256), 0, stream,
                       xT, packed, A, Dp, deltaT, Qbuf, SDbuf, cumd, yb, mem);
    hipLaunchKernelGGL(k_kvwo, dim3(128, 2), dim3(128), 0, stream,
                       mem, Wk, bk, Wv, bv, Wo, KTb, VWo);
    hipLaunchKernelGGL(k_attn, dim3(LL / 8, 2), dim3(256), 0, stream,
                       x, proj, yb, KTb, VWo, bo, out);
}